// Round 1
// baseline (272.512 us; speedup 1.0000x reference)
//
#include <hip/hip_runtime.h>
#include <hip/hip_bf16.h>

typedef __attribute__((ext_vector_type(8))) short short8;
typedef __attribute__((ext_vector_type(8))) unsigned short u16x8;
typedef __attribute__((ext_vector_type(4))) unsigned short u16x4;
typedef __attribute__((ext_vector_type(4))) float f32x4;

#define S_  2048
#define D_  1024
#define F3  3072   // 3 * D_H
#define LOG2E 1.4426950408889634f
#define C_SCALE (0.125f * LOG2E)   // 1/sqrt(64) folded into exp2

__device__ __forceinline__ unsigned short f2bf(float f) {
  unsigned int u = __builtin_bit_cast(unsigned int, f);
  u += 0x7fffu + ((u >> 16) & 1u);      // round-to-nearest-even
  return (unsigned short)(u >> 16);
}

// ---------------- x (f32) -> bf16 ----------------
__global__ __launch_bounds__(256) void conv_x_kernel(const float* __restrict__ x,
                                                     unsigned short* __restrict__ xb) {
  int i = (blockIdx.x * 256 + threadIdx.x) * 4;
  f32x4 v = *reinterpret_cast<const f32x4*>(&x[i]);
  u16x4 o;
  o[0] = f2bf(v[0]); o[1] = f2bf(v[1]); o[2] = f2bf(v[2]); o[3] = f2bf(v[3]);
  *reinterpret_cast<u16x4*>(&xb[i]) = o;
}

// ---------------- W [1024][3072] f32 -> Wt [3072][1024] bf16 ----------------
__global__ __launch_bounds__(256) void transpose_w_kernel(const float* __restrict__ W,
                                                          unsigned short* __restrict__ Wt) {
  __shared__ float tile[64][65];
  int nt = blockIdx.x;   // 48 tiles over N=3072
  int kt = blockIdx.y;   // 16 tiles over K=1024
  int tid = threadIdx.x;
#pragma unroll
  for (int i = 0; i < 16; i++) {
    int idx = tid + i * 256;
    int r = idx >> 6, c = idx & 63;
    tile[r][c] = W[(size_t)(kt * 64 + r) * F3 + nt * 64 + c];
  }
  __syncthreads();
#pragma unroll
  for (int i = 0; i < 16; i++) {
    int idx = tid + i * 256;
    int rn = idx >> 6, ck = idx & 63;
    Wt[(size_t)(nt * 64 + rn) * D_ + kt * 64 + ck] = f2bf(tile[ck][rn]);
  }
}

// ---------------- qkv[M,N] = xb[M,K] * Wt[N,K]^T + bias (bf16 in/out, f32 acc) ----
__global__ __launch_bounds__(256) void qkv_gemm_kernel(const unsigned short* __restrict__ A,
                                                       const unsigned short* __restrict__ Bt,
                                                       const float* __restrict__ bias,
                                                       unsigned short* __restrict__ C) {
  constexpr int K = D_;
  constexpr int N = F3;
  constexpr int LDK = 40;                 // 32 + 8 pad (keeps 16B align, breaks pow2 stride)
  __shared__ unsigned short sA[128 * LDK];
  __shared__ unsigned short sB[128 * LDK];
  int bn = blockIdx.x, bm = blockIdx.y;
  int tid = threadIdx.x;
  int wid = tid >> 6, lane = tid & 63;
  int wr = wid >> 1, wc = wid & 1;        // 2x2 wave grid, 64x64 each
  int lh = lane >> 4, l15 = lane & 15;
  f32x4 acc[4][4] = {};

  for (int k0 = 0; k0 < K; k0 += 32) {
#pragma unroll
    for (int i = 0; i < 2; i++) {
      int idx = tid + i * 256;            // 512 chunks of 8 bf16
      int row = idx >> 2;
      int col = (idx & 3) * 8;
      *reinterpret_cast<u16x8*>(&sA[row * LDK + col]) =
          *reinterpret_cast<const u16x8*>(&A[(size_t)(bm * 128 + row) * K + k0 + col]);
      *reinterpret_cast<u16x8*>(&sB[row * LDK + col]) =
          *reinterpret_cast<const u16x8*>(&Bt[(size_t)(bn * 128 + row) * K + k0 + col]);
    }
    __syncthreads();
    short8 af[4], bf[4];
#pragma unroll
    for (int m = 0; m < 4; m++)
      af[m] = *reinterpret_cast<const short8*>(&sA[(wr * 64 + m * 16 + l15) * LDK + lh * 8]);
#pragma unroll
    for (int n = 0; n < 4; n++)
      bf[n] = *reinterpret_cast<const short8*>(&sB[(wc * 64 + n * 16 + l15) * LDK + lh * 8]);
#pragma unroll
    for (int m = 0; m < 4; m++)
#pragma unroll
      for (int n = 0; n < 4; n++)
        acc[m][n] = __builtin_amdgcn_mfma_f32_16x16x32_bf16(af[m], bf[n], acc[m][n], 0, 0, 0);
    __syncthreads();
  }

  int row0 = bm * 128 + wr * 64;
  int col0 = bn * 128 + wc * 64;
#pragma unroll
  for (int m = 0; m < 4; m++)
#pragma unroll
    for (int n = 0; n < 4; n++) {
      int col = col0 + n * 16 + l15;
      float bv = bias[col];
#pragma unroll
      for (int r = 0; r < 4; r++) {
        int row = row0 + m * 16 + lh * 4 + r;   // C/D: col=lane&15, row=(lane>>4)*4+reg
        C[(size_t)row * N + col] = f2bf(acc[m][n][r] + bv);
      }
    }
}

// ---------------- causal flash attention ----------------
// qkv row s, head h: q = cols h*192+0..63, k = +64..127, v = +128..191
__global__ __launch_bounds__(256) void attn_kernel(const unsigned short* __restrict__ qkv,
                                                   float* __restrict__ out) {
  __shared__ unsigned short sK[32][72];       // [k][d], row-major, padded
  __shared__ unsigned short sVt[64][40];      // [d][k], transposed, padded
  __shared__ unsigned short sP[4][32][40];    // per-wave P tile [q][k]

  int bh = blockIdx.y;
  int b = bh >> 4, h = bh & 15;
  int qt = gridDim.x - 1 - blockIdx.x;        // heavy q-tiles first
  int tid = threadIdx.x;
  int wid = tid >> 6, lane = tid & 63;
  int lh = lane >> 4, l15 = lane & 15;

  const int rowb = b * S_;
  const int q0 = qt * 128;
  const int qc = h * 192;

  // Q fragments in registers: rows q0+wid*32+m*16+l15, d = c*32+lh*8
  short8 qf[2][2];
#pragma unroll
  for (int m = 0; m < 2; m++)
#pragma unroll
    for (int c = 0; c < 2; c++) {
      int qrow = q0 + wid * 32 + m * 16 + l15;
      qf[m][c] = *reinterpret_cast<const short8*>(
          &qkv[(size_t)(rowb + qrow) * F3 + qc + c * 32 + lh * 8]);
    }

  float mrow[2][4], lrow[2][4];
  f32x4 o[2][4];
#pragma unroll
  for (int m = 0; m < 2; m++) {
#pragma unroll
    for (int r = 0; r < 4; r++) { mrow[m][r] = -1e30f; lrow[m][r] = 0.f; }
#pragma unroll
    for (int d = 0; d < 4; d++) o[m][d] = (f32x4){0.f, 0.f, 0.f, 0.f};
  }

  int ktiles = (qt + 1) * 4;
  for (int kt = 0; kt < ktiles; kt++) {
    int kbase = kt * 32;
    {
      int krow = tid >> 3;                    // 0..31
      int kc = (tid & 7) * 8;                 // 0..56
      const size_t base = (size_t)(rowb + kbase + krow) * F3 + qc;
      u16x8 kv = *reinterpret_cast<const u16x8*>(&qkv[base + 64 + kc]);
      *reinterpret_cast<u16x8*>(&sK[krow][kc]) = kv;
      u16x8 vv = *reinterpret_cast<const u16x8*>(&qkv[base + 128 + kc]);
#pragma unroll
      for (int j = 0; j < 8; j++) sVt[kc + j][krow] = vv[j];
    }
    __syncthreads();

    // S = Q K^T (raw logits, scale folded into exp2 later)
    f32x4 s[2][2];
#pragma unroll
    for (int m = 0; m < 2; m++)
#pragma unroll
      for (int n = 0; n < 2; n++) {
        f32x4 a = {0.f, 0.f, 0.f, 0.f};
#pragma unroll
        for (int c = 0; c < 2; c++) {
          short8 kf = *reinterpret_cast<const short8*>(&sK[n * 16 + l15][c * 32 + lh * 8]);
          a = __builtin_amdgcn_mfma_f32_16x16x32_bf16(qf[m][c], kf, a, 0, 0, 0);
        }
        s[m][n] = a;
      }

    // online softmax per row (row = m*16 + lh*4 + r; cols spread over 16 lanes x 2 n-tiles)
#pragma unroll
    for (int m = 0; m < 2; m++) {
#pragma unroll
      for (int r = 0; r < 4; r++) {
        int qrow = q0 + wid * 32 + m * 16 + lh * 4 + r;
#pragma unroll
        for (int n = 0; n < 2; n++) {
          int kg = kbase + n * 16 + l15;
          if (kg > qrow) s[m][n][r] = -1e30f;   // causal mask (finite: no NaN traps)
        }
        float mx = fmaxf(s[m][0][r], s[m][1][r]);
#pragma unroll
        for (int off = 1; off < 16; off <<= 1) mx = fmaxf(mx, __shfl_xor(mx, off));
        float mold = mrow[m][r];
        float mnew = fmaxf(mold, mx);
        float scale = exp2f((mold - mnew) * C_SCALE);
        float psum = 0.f;
#pragma unroll
        for (int n = 0; n < 2; n++) {
          float p = exp2f((s[m][n][r] - mnew) * C_SCALE);
          s[m][n][r] = p;
          psum += p;
        }
#pragma unroll
        for (int off = 1; off < 16; off <<= 1) psum += __shfl_xor(psum, off);
        lrow[m][r] = lrow[m][r] * scale + psum;
        mrow[m][r] = mnew;
#pragma unroll
        for (int d = 0; d < 4; d++) o[m][d][r] *= scale;
        // stash P (bf16) for layout conversion C-layout -> A-layout
#pragma unroll
        for (int n = 0; n < 2; n++)
          sP[wid][m * 16 + lh * 4 + r][n * 16 + l15] = f2bf(s[m][n][r]);
      }
    }

    // O += P V  (A-frag: row=l15, k=lh*8..; B-frag from Vt: col=l15 (d), k contiguous)
#pragma unroll
    for (int m = 0; m < 2; m++) {
      short8 pf = *reinterpret_cast<const short8*>(&sP[wid][m * 16 + l15][lh * 8]);
#pragma unroll
      for (int d = 0; d < 4; d++) {
        short8 vf = *reinterpret_cast<const short8*>(&sVt[d * 16 + l15][lh * 8]);
        o[m][d] = __builtin_amdgcn_mfma_f32_16x16x32_bf16(pf, vf, o[m][d], 0, 0, 0);
      }
    }
    __syncthreads();   // protect sK/sVt before next stage
  }

  // epilogue: out[b][q][h*64 + d] = o / l
#pragma unroll
  for (int m = 0; m < 2; m++)
#pragma unroll
    for (int r = 0; r < 4; r++) {
      int qrow = q0 + wid * 32 + m * 16 + lh * 4 + r;
      float inv = 1.f / lrow[m][r];
      float* op = &out[(size_t)(rowb + qrow) * D_ + h * 64];
#pragma unroll
      for (int d = 0; d < 4; d++) op[d * 16 + l15] = o[m][d][r] * inv;
    }
}

extern "C" void kernel_launch(void* const* d_in, const int* in_sizes, int n_in,
                              void* d_out, int out_size, void* d_ws, size_t ws_size,
                              hipStream_t stream) {
  const float* x    = (const float*)d_in[0];
  const float* W    = (const float*)d_in[1];
  const float* bias = (const float*)d_in[2];
  float* out = (float*)d_out;
  char* ws = (char*)d_ws;
  unsigned short* xb  = (unsigned short*)(ws);                    // 8 MB
  unsigned short* wt  = (unsigned short*)(ws + (8u << 20));       // 6 MB
  unsigned short* qkv = (unsigned short*)(ws + (14u << 20));      // 24 MB

  conv_x_kernel<<<4096, 256, 0, stream>>>(x, xb);
  transpose_w_kernel<<<dim3(48, 16), 256, 0, stream>>>(W, wt);
  qkv_gemm_kernel<<<dim3(24, 32), 256, 0, stream>>>(xb, wt, bias, qkv);
  attn_kernel<<<dim3(16, 32), 256, 0, stream>>>(qkv, out);
}

// Round 2
// 168.560 us; speedup vs baseline: 1.6167x; 1.6167x over previous
//
#include <hip/hip_runtime.h>
#include <hip/hip_bf16.h>

typedef __attribute__((ext_vector_type(8))) short short8;
typedef __attribute__((ext_vector_type(8))) unsigned short u16x8;
typedef __attribute__((ext_vector_type(4))) unsigned short u16x4;
typedef __attribute__((ext_vector_type(2))) unsigned short u16x2;
typedef __attribute__((ext_vector_type(4))) float f32x4;

#define S_  2048
#define D_  1024
#define F3  3072   // 3 * D_H
#define LOG2E 1.4426950408889634f
#define C_SCALE (0.125f * LOG2E)   // 1/sqrt(64) folded into exp2

__device__ __forceinline__ unsigned short f2bf(float f) {
  unsigned int u = __builtin_bit_cast(unsigned int, f);
  u += 0x7fffu + ((u >> 16) & 1u);      // round-to-nearest-even
  return (unsigned short)(u >> 16);
}

__device__ __forceinline__ float fast_exp2(float x) {
  float r;
  asm("v_exp_f32 %0, %1" : "=v"(r) : "v"(x));
  return r;
}

// ---------------- x (f32) -> bf16 ----------------
__global__ __launch_bounds__(256) void conv_x_kernel(const float* __restrict__ x,
                                                     unsigned short* __restrict__ xb) {
  int i = (blockIdx.x * 256 + threadIdx.x) * 4;
  f32x4 v = *reinterpret_cast<const f32x4*>(&x[i]);
  u16x4 o;
  o[0] = f2bf(v[0]); o[1] = f2bf(v[1]); o[2] = f2bf(v[2]); o[3] = f2bf(v[3]);
  *reinterpret_cast<u16x4*>(&xb[i]) = o;
}

// ---------------- W [1024][3072] f32 -> Wt [3072][1024] bf16 ----------------
__global__ __launch_bounds__(256) void transpose_w_kernel(const float* __restrict__ W,
                                                          unsigned short* __restrict__ Wt) {
  __shared__ float tile[64][65];
  int nt = blockIdx.x;   // 48 tiles over N=3072
  int kt = blockIdx.y;   // 16 tiles over K=1024
  int tid = threadIdx.x;
#pragma unroll
  for (int i = 0; i < 16; i++) {
    int idx = tid + i * 256;
    int r = idx >> 6, c = idx & 63;
    tile[r][c] = W[(size_t)(kt * 64 + r) * F3 + nt * 64 + c];
  }
  __syncthreads();
#pragma unroll
  for (int i = 0; i < 16; i++) {
    int idx = tid + i * 256;
    int rn = idx >> 6, ck = idx & 63;
    Wt[(size_t)(nt * 64 + rn) * D_ + kt * 64 + ck] = f2bf(tile[ck][rn]);
  }
}

// ---------------- qkv[M,N] = xb[M,K] * Wt[N,K]^T + bias (bf16 in/out, f32 acc) ----
__global__ __launch_bounds__(256) void qkv_gemm_kernel(const unsigned short* __restrict__ A,
                                                       const unsigned short* __restrict__ Bt,
                                                       const float* __restrict__ bias,
                                                       unsigned short* __restrict__ C) {
  constexpr int K = D_;
  constexpr int N = F3;
  constexpr int LDK = 40;
  __shared__ unsigned short sA[128 * LDK];
  __shared__ unsigned short sB[128 * LDK];
  int bn = blockIdx.x, bm = blockIdx.y;
  int tid = threadIdx.x;
  int wid = tid >> 6, lane = tid & 63;
  int wr = wid >> 1, wc = wid & 1;
  int lh = lane >> 4, l15 = lane & 15;
  f32x4 acc[4][4] = {};

  for (int k0 = 0; k0 < K; k0 += 32) {
#pragma unroll
    for (int i = 0; i < 2; i++) {
      int idx = tid + i * 256;
      int row = idx >> 2;
      int col = (idx & 3) * 8;
      *reinterpret_cast<u16x8*>(&sA[row * LDK + col]) =
          *reinterpret_cast<const u16x8*>(&A[(size_t)(bm * 128 + row) * K + k0 + col]);
      *reinterpret_cast<u16x8*>(&sB[row * LDK + col]) =
          *reinterpret_cast<const u16x8*>(&Bt[(size_t)(bn * 128 + row) * K + k0 + col]);
    }
    __syncthreads();
    short8 af[4], bf[4];
#pragma unroll
    for (int m = 0; m < 4; m++)
      af[m] = *reinterpret_cast<const short8*>(&sA[(wr * 64 + m * 16 + l15) * LDK + lh * 8]);
#pragma unroll
    for (int n = 0; n < 4; n++)
      bf[n] = *reinterpret_cast<const short8*>(&sB[(wc * 64 + n * 16 + l15) * LDK + lh * 8]);
#pragma unroll
    for (int m = 0; m < 4; m++)
#pragma unroll
      for (int n = 0; n < 4; n++)
        acc[m][n] = __builtin_amdgcn_mfma_f32_16x16x32_bf16(af[m], bf[n], acc[m][n], 0, 0, 0);
    __syncthreads();
  }

  int row0 = bm * 128 + wr * 64;
  int col0 = bn * 128 + wc * 64;
#pragma unroll
  for (int m = 0; m < 4; m++)
#pragma unroll
    for (int n = 0; n < 4; n++) {
      int col = col0 + n * 16 + l15;
      float bv = bias[col];
#pragma unroll
      for (int r = 0; r < 4; r++) {
        int row = row0 + m * 16 + lh * 4 + r;
        C[(size_t)row * N + col] = f2bf(acc[m][n][r] + bv);
      }
    }
}

// ---------------- causal flash attention (rewritten) ----------------
// Block = (pair p, bh). Processes q-strip qt=p then qt=31-p (QB=64 rows each,
// 4 waves x 16 rows). KVBLK=64, reg-staged double buffer, 1 barrier / k-tile.
// All LDS tiles are 64 shorts (128 B) per row with XOR swizzle:
//   byte ^= ((row&7) ^ ((row>>3)&7)) << 4
// (row>>3 term makes transposed V writes ~2-way instead of 8-way).

__device__ __forceinline__ int swzs(int row, int cols) {   // -> short index
  int byte = row * 128 + cols * 2;
  byte ^= (((row & 7) ^ ((row >> 3) & 7)) << 4);
  return byte >> 1;
}

struct Stage {
  u16x8 k0, k1, va, vb;
};

// base = qkv + (rowb + kbase) * F3 + h*192
__device__ __forceinline__ void stage_load(Stage& st, const unsigned short* __restrict__ base,
                                           int tid) {
  int r0 = tid >> 3;              // 0..31
  int c8 = (tid & 7) * 8;         // 0..56
  st.k0 = *reinterpret_cast<const u16x8*>(base + (size_t)r0 * F3 + 64 + c8);
  st.k1 = *reinterpret_cast<const u16x8*>(base + (size_t)(r0 + 32) * F3 + 64 + c8);
  st.va = *reinterpret_cast<const u16x8*>(base + (size_t)(2 * r0) * F3 + 128 + c8);
  st.vb = *reinterpret_cast<const u16x8*>(base + (size_t)(2 * r0 + 1) * F3 + 128 + c8);
}

__device__ __forceinline__ void stage_write(const Stage& st, unsigned short* sk,
                                            unsigned short* sv, int tid) {
  int r0 = tid >> 3;
  int c8 = (tid & 7) * 8;
  *reinterpret_cast<u16x8*>(sk + swzs(r0, c8)) = st.k0;
  *reinterpret_cast<u16x8*>(sk + swzs(r0 + 32, c8)) = st.k1;
#pragma unroll
  for (int j = 0; j < 8; j++) {
    u16x2 t2;
    t2[0] = st.va[j];
    t2[1] = st.vb[j];
    *reinterpret_cast<u16x2*>(sv + swzs(c8 + j, 2 * r0)) = t2;   // sVt[d][k] pair
  }
}

__global__ __launch_bounds__(256) void attn_kernel(const unsigned short* __restrict__ qkv,
                                                   float* __restrict__ out) {
  __shared__ unsigned short sK[2][4096];    // [64 k][64 d] swizzled
  __shared__ unsigned short sVt[2][4096];   // [64 d][64 k] swizzled
  __shared__ unsigned short sP[4][1024];    // per-wave [16 q][64 k] swizzled

  const int p = blockIdx.x;                 // 0..15 (strip pair)
  const int bh = blockIdx.y;
  const int b = bh >> 4, h = bh & 15;
  const int tid = threadIdx.x;
  const int wid = tid >> 6, lane = tid & 63;
  const int lh = lane >> 4, l15 = lane & 15;
  const int rowb = b * S_;
  const unsigned short* qbase = qkv + (size_t)rowb * F3 + h * 192;
  unsigned short* myP = sP[wid];

#pragma unroll 1
  for (int ph = 0; ph < 2; ph++) {
    const int qt = ph ? (31 - p) : p;
    const int ktiles = qt + 1;
    const int qrow_lo = qt * 64 + wid * 16;

    short8 qf[2];
#pragma unroll
    for (int c = 0; c < 2; c++)
      qf[c] = *reinterpret_cast<const short8*>(
          qbase + (size_t)(qrow_lo + l15) * F3 + c * 32 + lh * 8);

    float mrow[4], lrow[4];
    f32x4 o[4];
#pragma unroll
    for (int r = 0; r < 4; r++) { mrow[r] = -1e30f; lrow[r] = 0.f; }
#pragma unroll
    for (int d = 0; d < 4; d++) o[d] = (f32x4){0.f, 0.f, 0.f, 0.f};

    Stage st;
    stage_load(st, qbase, tid);             // tile 0
    __syncthreads();                        // prev phase done reading buffers
    stage_write(st, sK[0], sVt[0], tid);
    __syncthreads();

    for (int t = 0; t < ktiles; t++) {
      const int cur = t & 1;
      if (t + 1 < ktiles)
        stage_load(st, qbase + (size_t)(t + 1) * 64 * F3, tid);

      // S = Q K^T over 64 k-cols (4 n-tiles)
      f32x4 s[4];
#pragma unroll
      for (int n = 0; n < 4; n++) {
        f32x4 a = {0.f, 0.f, 0.f, 0.f};
#pragma unroll
        for (int c = 0; c < 2; c++) {
          short8 kf = *reinterpret_cast<const short8*>(
              &sK[cur][swzs(n * 16 + l15, c * 32 + lh * 8)]);
          a = __builtin_amdgcn_mfma_f32_16x16x32_bf16(qf[c], kf, a, 0, 0, 0);
        }
        s[n] = a;
      }

      const bool last = (t == qt);          // only diagonal tile needs masking
      const int kbase = t * 64;

#pragma unroll
      for (int r = 0; r < 4; r++) {
        const int qrow = qrow_lo + lh * 4 + r;
        if (last) {
#pragma unroll
          for (int n = 0; n < 4; n++)
            if (kbase + n * 16 + l15 > qrow) s[n][r] = -1e30f;
        }
        float mx = fmaxf(fmaxf(s[0][r], s[1][r]), fmaxf(s[2][r], s[3][r]));
#pragma unroll
        for (int off = 1; off < 16; off <<= 1) mx = fmaxf(mx, __shfl_xor(mx, off));
        float mold = mrow[r];
        float mnew = fmaxf(mold, mx);
        float scl = fast_exp2((mold - mnew) * C_SCALE);
        float mC = mnew * C_SCALE;
        float ps = 0.f;
#pragma unroll
        for (int n = 0; n < 4; n++) {
          float pv = fast_exp2(fmaf(s[n][r], C_SCALE, -mC));
          s[n][r] = pv;
          ps += pv;
        }
#pragma unroll
        for (int off = 1; off < 16; off <<= 1) ps += __shfl_xor(ps, off);
        lrow[r] = lrow[r] * scl + ps;
        mrow[r] = mnew;
#pragma unroll
        for (int d = 0; d < 4; d++) o[d][r] *= scl;
#pragma unroll
        for (int n = 0; n < 4; n++)
          myP[swzs(lh * 4 + r, n * 16 + l15)] = f2bf(s[n][r]);
      }

      // O += P V  (per-wave sP; DS ops in-order within wave)
      short8 pf[2];
#pragma unroll
      for (int ks = 0; ks < 2; ks++)
        pf[ks] = *reinterpret_cast<const short8*>(&myP[swzs(l15, ks * 32 + lh * 8)]);
#pragma unroll
      for (int d = 0; d < 4; d++) {
#pragma unroll
        for (int ks = 0; ks < 2; ks++) {
          short8 vf = *reinterpret_cast<const short8*>(
              &sVt[cur][swzs(d * 16 + l15, ks * 32 + lh * 8)]);
          o[d] = __builtin_amdgcn_mfma_f32_16x16x32_bf16(pf[ks], vf, o[d], 0, 0, 0);
        }
      }

      if (t + 1 < ktiles) {
        stage_write(st, sK[cur ^ 1], sVt[cur ^ 1], tid);
        __syncthreads();
      }
    }

    // epilogue
#pragma unroll
    for (int r = 0; r < 4; r++) {
      const int qrow = qrow_lo + lh * 4 + r;
      float inv = 1.f / lrow[r];
      float* op = &out[(size_t)(rowb + qrow) * D_ + h * 64];
#pragma unroll
      for (int d = 0; d < 4; d++) op[d * 16 + l15] = o[d][r] * inv;
    }
  }
}

extern "C" void kernel_launch(void* const* d_in, const int* in_sizes, int n_in,
                              void* d_out, int out_size, void* d_ws, size_t ws_size,
                              hipStream_t stream) {
  const float* x    = (const float*)d_in[0];
  const float* W    = (const float*)d_in[1];
  const float* bias = (const float*)d_in[2];
  float* out = (float*)d_out;
  char* ws = (char*)d_ws;
  unsigned short* xb  = (unsigned short*)(ws);                    // 8 MB
  unsigned short* wt  = (unsigned short*)(ws + (8u << 20));       // 6 MB
  unsigned short* qkv = (unsigned short*)(ws + (14u << 20));      // 24 MB

  conv_x_kernel<<<4096, 256, 0, stream>>>(x, xb);
  transpose_w_kernel<<<dim3(48, 16), 256, 0, stream>>>(W, wt);
  qkv_gemm_kernel<<<dim3(24, 32), 256, 0, stream>>>(xb, wt, bias, qkv);
  attn_kernel<<<dim3(16, 32), 256, 0, stream>>>(qkv, out);
}

// Round 3
// 159.917 us; speedup vs baseline: 1.7041x; 1.0540x over previous
//
#include <hip/hip_runtime.h>
#include <hip/hip_bf16.h>

typedef __attribute__((ext_vector_type(8))) short short8;
typedef __attribute__((ext_vector_type(8))) unsigned short u16x8;
typedef __attribute__((ext_vector_type(4))) unsigned short u16x4;
typedef __attribute__((ext_vector_type(2))) unsigned short u16x2;
typedef __attribute__((ext_vector_type(4))) float f32x4;

#define S_  2048
#define D_  1024
#define F3  3072   // 3 * D_H
#define LOG2E 1.4426950408889634f
#define C_SCALE (0.125f * LOG2E)   // 1/sqrt(64) folded into exp2

__device__ __forceinline__ unsigned short f2bf(float f) {
  unsigned int u = __builtin_bit_cast(unsigned int, f);
  u += 0x7fffu + ((u >> 16) & 1u);      // round-to-nearest-even
  return (unsigned short)(u >> 16);
}

__device__ __forceinline__ float fast_exp2(float x) {
  float r;
  asm("v_exp_f32 %0, %1" : "=v"(r) : "v"(x));
  return r;
}

// ---------------- x (f32) -> bf16 ----------------
__global__ __launch_bounds__(256) void conv_x_kernel(const float* __restrict__ x,
                                                     unsigned short* __restrict__ xb) {
  int i = (blockIdx.x * 256 + threadIdx.x) * 4;
  f32x4 v = *reinterpret_cast<const f32x4*>(&x[i]);
  u16x4 o;
  o[0] = f2bf(v[0]); o[1] = f2bf(v[1]); o[2] = f2bf(v[2]); o[3] = f2bf(v[3]);
  *reinterpret_cast<u16x4*>(&xb[i]) = o;
}

// ---------------- W [1024][3072] f32 -> Wt [3072][1024] bf16 ----------------
__global__ __launch_bounds__(256) void transpose_w_kernel(const float* __restrict__ W,
                                                          unsigned short* __restrict__ Wt) {
  __shared__ float tile[64][65];
  int nt = blockIdx.x;
  int kt = blockIdx.y;
  int tid = threadIdx.x;
#pragma unroll
  for (int i = 0; i < 16; i++) {
    int idx = tid + i * 256;
    int r = idx >> 6, c = idx & 63;
    tile[r][c] = W[(size_t)(kt * 64 + r) * F3 + nt * 64 + c];
  }
  __syncthreads();
#pragma unroll
  for (int i = 0; i < 16; i++) {
    int idx = tid + i * 256;
    int rn = idx >> 6, ck = idx & 63;
    Wt[(size_t)(nt * 64 + rn) * D_ + kt * 64 + ck] = f2bf(tile[ck][rn]);
  }
}

// ---------------- qkv[M,N] = xb[M,K] * Wt[N,K]^T + bias (bf16 in/out, f32 acc) ----
__global__ __launch_bounds__(256) void qkv_gemm_kernel(const unsigned short* __restrict__ A,
                                                       const unsigned short* __restrict__ Bt,
                                                       const float* __restrict__ bias,
                                                       unsigned short* __restrict__ C) {
  constexpr int K = D_;
  constexpr int N = F3;
  constexpr int LDK = 40;
  __shared__ unsigned short sA[128 * LDK];
  __shared__ unsigned short sB[128 * LDK];
  int bn = blockIdx.x, bm = blockIdx.y;
  int tid = threadIdx.x;
  int wid = tid >> 6, lane = tid & 63;
  int wr = wid >> 1, wc = wid & 1;
  int lh = lane >> 4, l15 = lane & 15;
  f32x4 acc[4][4] = {};

  for (int k0 = 0; k0 < K; k0 += 32) {
#pragma unroll
    for (int i = 0; i < 2; i++) {
      int idx = tid + i * 256;
      int row = idx >> 2;
      int col = (idx & 3) * 8;
      *reinterpret_cast<u16x8*>(&sA[row * LDK + col]) =
          *reinterpret_cast<const u16x8*>(&A[(size_t)(bm * 128 + row) * K + k0 + col]);
      *reinterpret_cast<u16x8*>(&sB[row * LDK + col]) =
          *reinterpret_cast<const u16x8*>(&Bt[(size_t)(bn * 128 + row) * K + k0 + col]);
    }
    __syncthreads();
    short8 af[4], bf[4];
#pragma unroll
    for (int m = 0; m < 4; m++)
      af[m] = *reinterpret_cast<const short8*>(&sA[(wr * 64 + m * 16 + l15) * LDK + lh * 8]);
#pragma unroll
    for (int n = 0; n < 4; n++)
      bf[n] = *reinterpret_cast<const short8*>(&sB[(wc * 64 + n * 16 + l15) * LDK + lh * 8]);
#pragma unroll
    for (int m = 0; m < 4; m++)
#pragma unroll
      for (int n = 0; n < 4; n++)
        acc[m][n] = __builtin_amdgcn_mfma_f32_16x16x32_bf16(af[m], bf[n], acc[m][n], 0, 0, 0);
    __syncthreads();
  }

  int row0 = bm * 128 + wr * 64;
  int col0 = bn * 128 + wc * 64;
#pragma unroll
  for (int m = 0; m < 4; m++)
#pragma unroll
    for (int n = 0; n < 4; n++) {
      int col = col0 + n * 16 + l15;
      float bv = bias[col];
#pragma unroll
      for (int r = 0; r < 4; r++) {
        int row = row0 + m * 16 + lh * 4 + r;
        C[(size_t)row * N + col] = f2bf(acc[m][n][r] + bv);
      }
    }
}

// ---------------- causal flash attention (swapped-QK^T, lane-local softmax) -----
// One block per (strip qt, bh): 4 waves x 16 q-rows, QB=64, KVBLK=64.
// S^T = mfma(K, Q): lane l15 = q, holds 16 k-values in regs -> softmax is
// 15 in-lane ops + 2 shfl. O^T = mfma(V^T, P): lane l15 = q, d in rows.
// 1024 blocks, all resident (40KB LDS -> 4 blocks/CU); strip scramble
// qt=(bx+by)&31 decorrelates per-CU load.

__device__ __forceinline__ int swzs(int row, int cols) {   // -> short index
  int byte = row * 128 + cols * 2;
  byte ^= (((row & 7) ^ ((row >> 3) & 7)) << 4);
  return byte >> 1;
}

struct Stage {
  u16x8 k0, k1, va, vb;
};

__device__ __forceinline__ void stage_load(Stage& st, const unsigned short* __restrict__ base,
                                           int tid) {
  int r0 = tid >> 3;              // 0..31
  int c8 = (tid & 7) * 8;         // 0..56
  st.k0 = *reinterpret_cast<const u16x8*>(base + (size_t)r0 * F3 + 64 + c8);
  st.k1 = *reinterpret_cast<const u16x8*>(base + (size_t)(r0 + 32) * F3 + 64 + c8);
  st.va = *reinterpret_cast<const u16x8*>(base + (size_t)(2 * r0) * F3 + 128 + c8);
  st.vb = *reinterpret_cast<const u16x8*>(base + (size_t)(2 * r0 + 1) * F3 + 128 + c8);
}

__device__ __forceinline__ void stage_write(const Stage& st, unsigned short* sk,
                                            unsigned short* sv, int tid) {
  int r0 = tid >> 3;
  int c8 = (tid & 7) * 8;
  *reinterpret_cast<u16x8*>(sk + swzs(r0, c8)) = st.k0;
  *reinterpret_cast<u16x8*>(sk + swzs(r0 + 32, c8)) = st.k1;
#pragma unroll
  for (int j = 0; j < 8; j++) {
    u16x2 t2;
    t2[0] = st.va[j];
    t2[1] = st.vb[j];
    *reinterpret_cast<u16x2*>(sv + swzs(c8 + j, 2 * r0)) = t2;   // sVt[d][k] pair
  }
}

__global__ __launch_bounds__(256, 4) void attn_kernel(const unsigned short* __restrict__ qkv,
                                                      float* __restrict__ out) {
  __shared__ unsigned short sK[2][4096];    // [64 k][64 d] swizzled
  __shared__ unsigned short sVt[2][4096];   // [64 d][64 k] swizzled
  __shared__ unsigned short sP[4][1024];    // per-wave [16 q][64 k] swizzled

  const int qt = (blockIdx.x + blockIdx.y) & 31;
  const int bh = blockIdx.y;
  const int b = bh >> 4, h = bh & 15;
  const int tid = threadIdx.x;
  const int wid = tid >> 6, lane = tid & 63;
  const int lh = lane >> 4, l15 = lane & 15;
  const int rowb = b * S_;
  const unsigned short* qbase = qkv + (size_t)rowb * F3 + h * 192;
  unsigned short* myP = sP[wid];

  const int ktiles = qt + 1;
  const int qrow_lo = qt * 64 + wid * 16;
  const int qrow = qrow_lo + l15;           // this lane's q-row

  // Q fragments (B-operand): lane l15 = q-row, lh*8 = k-dim offset
  short8 qf[2];
#pragma unroll
  for (int c = 0; c < 2; c++)
    qf[c] = *reinterpret_cast<const short8*>(
        qbase + (size_t)qrow * F3 + c * 32 + lh * 8);

  float m_s = -1e30f, l_s = 0.f;
  f32x4 o[4];
#pragma unroll
  for (int d = 0; d < 4; d++) o[d] = (f32x4){0.f, 0.f, 0.f, 0.f};

  Stage st;
  stage_load(st, qbase, tid);
  stage_write(st, sK[0], sVt[0], tid);
  __syncthreads();

  for (int t = 0; t < ktiles; t++) {
    const int cur = t & 1;
    if (t + 1 < ktiles)
      stage_load(st, qbase + (size_t)(t + 1) * 64 * F3, tid);

    // S^T = K Q^T : s[n][r] = S[q=l15][k = t*64 + n*16 + lh*4 + r]
    f32x4 s[4];
#pragma unroll
    for (int n = 0; n < 4; n++) {
      f32x4 a = {0.f, 0.f, 0.f, 0.f};
#pragma unroll
      for (int c = 0; c < 2; c++) {
        short8 kf = *reinterpret_cast<const short8*>(
            &sK[cur][swzs(n * 16 + l15, c * 32 + lh * 8)]);
        a = __builtin_amdgcn_mfma_f32_16x16x32_bf16(kf, qf[c], a, 0, 0, 0);
      }
      s[n] = a;
    }

    if (t == qt) {                          // diagonal tile: causal mask
      const int kbase = t * 64;
#pragma unroll
      for (int n = 0; n < 4; n++)
#pragma unroll
        for (int r = 0; r < 4; r++)
          if (kbase + n * 16 + lh * 4 + r > qrow) s[n][r] = -1e30f;
    }

    // lane-local softmax (lane = one q-row; 16 k-values in regs)
    float mx = fmaxf(fmaxf(fmaxf(s[0][0], s[0][1]), fmaxf(s[0][2], s[0][3])),
                     fmaxf(fmaxf(s[1][0], s[1][1]), fmaxf(s[1][2], s[1][3])));
    mx = fmaxf(mx, fmaxf(fmaxf(fmaxf(s[2][0], s[2][1]), fmaxf(s[2][2], s[2][3])),
                         fmaxf(fmaxf(s[3][0], s[3][1]), fmaxf(s[3][2], s[3][3]))));
    mx = fmaxf(mx, __shfl_xor(mx, 16));
    mx = fmaxf(mx, __shfl_xor(mx, 32));

    if (!__all(mx <= m_s)) {                // defer-max: skip rescale when max unchanged
      float mnew = fmaxf(m_s, mx);
      float scl = fast_exp2((m_s - mnew) * C_SCALE);
      m_s = mnew;
      l_s *= scl;
#pragma unroll
      for (int d = 0; d < 4; d++) o[d] *= scl;
    }

    float mC = m_s * C_SCALE;
    float ps = 0.f;
#pragma unroll
    for (int n = 0; n < 4; n++)
#pragma unroll
      for (int r = 0; r < 4; r++) {
        float pv = fast_exp2(fmaf(s[n][r], C_SCALE, -mC));
        s[n][r] = pv;
        ps += pv;
      }
    ps += __shfl_xor(ps, 16);
    ps += __shfl_xor(ps, 32);
    l_s += ps;

    // P store: row q=l15, cols n*16+lh*4..+3 (one b64 per n)
#pragma unroll
    for (int n = 0; n < 4; n++) {
      u16x4 pk;
      pk[0] = f2bf(s[n][0]); pk[1] = f2bf(s[n][1]);
      pk[2] = f2bf(s[n][2]); pk[3] = f2bf(s[n][3]);
      *reinterpret_cast<u16x4*>(&myP[swzs(l15, n * 16 + lh * 4)]) = pk;
    }

    // O^T += V^T P : A = V^T (rows d), B = P (rows q)
    short8 pf[2];
#pragma unroll
    for (int ks = 0; ks < 2; ks++)
      pf[ks] = *reinterpret_cast<const short8*>(&myP[swzs(l15, ks * 32 + lh * 8)]);
#pragma unroll
    for (int d = 0; d < 4; d++)
#pragma unroll
      for (int ks = 0; ks < 2; ks++) {
        short8 vf = *reinterpret_cast<const short8*>(
            &sVt[cur][swzs(d * 16 + l15, ks * 32 + lh * 8)]);
        o[d] = __builtin_amdgcn_mfma_f32_16x16x32_bf16(vf, pf[ks], o[d], 0, 0, 0);
      }

    if (t + 1 < ktiles) {
      stage_write(st, sK[cur ^ 1], sVt[cur ^ 1], tid);
      __syncthreads();
    }
  }

  // epilogue: lane l15 = q; o[d][r] = O[q][d*16 + lh*4 + r] -> contiguous f32x4
  float inv = 1.f / l_s;
  float* op = &out[(size_t)(rowb + qrow) * D_ + h * 64];
#pragma unroll
  for (int d = 0; d < 4; d++) {
    f32x4 v = o[d];
    v[0] *= inv; v[1] *= inv; v[2] *= inv; v[3] *= inv;
    *reinterpret_cast<f32x4*>(&op[d * 16 + lh * 4]) = v;
  }
}

extern "C" void kernel_launch(void* const* d_in, const int* in_sizes, int n_in,
                              void* d_out, int out_size, void* d_ws, size_t ws_size,
                              hipStream_t stream) {
  const float* x    = (const float*)d_in[0];
  const float* W    = (const float*)d_in[1];
  const float* bias = (const float*)d_in[2];
  float* out = (float*)d_out;
  char* ws = (char*)d_ws;
  unsigned short* xb  = (unsigned short*)(ws);                    // 8 MB
  unsigned short* wt  = (unsigned short*)(ws + (8u << 20));       // 6 MB
  unsigned short* qkv = (unsigned short*)(ws + (14u << 20));      // 24 MB

  conv_x_kernel<<<4096, 256, 0, stream>>>(x, xb);
  transpose_w_kernel<<<dim3(48, 16), 256, 0, stream>>>(W, wt);
  qkv_gemm_kernel<<<dim3(24, 32), 256, 0, stream>>>(xb, wt, bias, qkv);
  attn_kernel<<<dim3(32, 32), 256, 0, stream>>>(qkv, out);
}

// Round 4
// 123.906 us; speedup vs baseline: 2.1993x; 1.2906x over previous
//
#include <hip/hip_runtime.h>
#include <hip/hip_bf16.h>

typedef __attribute__((ext_vector_type(8))) short short8;
typedef __attribute__((ext_vector_type(8))) unsigned short u16x8;
typedef __attribute__((ext_vector_type(4))) unsigned short u16x4;
typedef __attribute__((ext_vector_type(4))) float f32x4;
typedef __attribute__((ext_vector_type(16))) float f32x16;

#define S_  2048
#define D_  1024
#define F3  3072
#define QKLD 2048                  // qk buffer: row s -> [h][q 64 | k 64]
#define LOG2E 1.4426950408889634f
#define C_SCALE (0.125f * LOG2E)   // 1/sqrt(64) folded into exp2

__device__ __forceinline__ unsigned short f2bf(float f) {
  unsigned int u = __builtin_bit_cast(unsigned int, f);
  u += 0x7fffu + ((u >> 16) & 1u);
  return (unsigned short)(u >> 16);
}
__device__ __forceinline__ unsigned short f2bf_trunc(float f) {
  return (unsigned short)(__builtin_bit_cast(unsigned int, f) >> 16);
}
__device__ __forceinline__ float fast_exp2(float x) {
  float r;
  asm("v_exp_f32 %0, %1" : "=v"(r) : "v"(x));
  return r;
}

// ---------------- x (f32) -> bf16 ----------------
__global__ __launch_bounds__(256) void conv_x_kernel(const float* __restrict__ x,
                                                     unsigned short* __restrict__ xb) {
  int i = (blockIdx.x * 256 + threadIdx.x) * 4;
  f32x4 v = *reinterpret_cast<const f32x4*>(&x[i]);
  u16x4 o;
  o[0] = f2bf(v[0]); o[1] = f2bf(v[1]); o[2] = f2bf(v[2]); o[3] = f2bf(v[3]);
  *reinterpret_cast<u16x4*>(&xb[i]) = o;
}

// ---------------- W [1024][3072] f32 -> Wt [3072][1024] bf16 ----------------
__global__ __launch_bounds__(256) void transpose_w_kernel(const float* __restrict__ W,
                                                          unsigned short* __restrict__ Wt) {
  __shared__ float tile[64][65];
  int nt = blockIdx.x;
  int kt = blockIdx.y;
  int tid = threadIdx.x;
#pragma unroll
  for (int i = 0; i < 16; i++) {
    int idx = tid + i * 256;
    int r = idx >> 6, c = idx & 63;
    tile[r][c] = W[(size_t)(kt * 64 + r) * F3 + nt * 64 + c];
  }
  __syncthreads();
#pragma unroll
  for (int i = 0; i < 16; i++) {
    int idx = tid + i * 256;
    int rn = idx >> 6, ck = idx & 63;
    Wt[(size_t)(nt * 64 + rn) * D_ + kt * 64 + ck] = f2bf(tile[ck][rn]);
  }
}

// ------- GEMM: qk/vT = xb[M,K] * Wt[N,K]^T + bias; V columns written transposed -----
__global__ __launch_bounds__(256) void qkv_gemm_kernel(const unsigned short* __restrict__ A,
                                                       const unsigned short* __restrict__ Bt,
                                                       const float* __restrict__ bias,
                                                       unsigned short* __restrict__ qk,
                                                       unsigned short* __restrict__ vT) {
  constexpr int K = D_;
  constexpr int LDK = 40;
  __shared__ unsigned short sA[128 * LDK];
  __shared__ unsigned short sB[128 * LDK];
  int bn = blockIdx.x, bm = blockIdx.y;
  int tid = threadIdx.x;
  int wid = tid >> 6, lane = tid & 63;
  int wr = wid >> 1, wc = wid & 1;
  int lh = lane >> 4, l15 = lane & 15;
  f32x4 acc[4][4] = {};

  for (int k0 = 0; k0 < K; k0 += 32) {
#pragma unroll
    for (int i = 0; i < 2; i++) {
      int idx = tid + i * 256;
      int row = idx >> 2;
      int col = (idx & 3) * 8;
      *reinterpret_cast<u16x8*>(&sA[row * LDK + col]) =
          *reinterpret_cast<const u16x8*>(&A[(size_t)(bm * 128 + row) * K + k0 + col]);
      *reinterpret_cast<u16x8*>(&sB[row * LDK + col]) =
          *reinterpret_cast<const u16x8*>(&Bt[(size_t)(bn * 128 + row) * K + k0 + col]);
    }
    __syncthreads();
    short8 af[4], bf[4];
#pragma unroll
    for (int m = 0; m < 4; m++)
      af[m] = *reinterpret_cast<const short8*>(&sA[(wr * 64 + m * 16 + l15) * LDK + lh * 8]);
#pragma unroll
    for (int n = 0; n < 4; n++)
      bf[n] = *reinterpret_cast<const short8*>(&sB[(wc * 64 + n * 16 + l15) * LDK + lh * 8]);
#pragma unroll
    for (int m = 0; m < 4; m++)
#pragma unroll
      for (int n = 0; n < 4; n++)
        acc[m][n] = __builtin_amdgcn_mfma_f32_16x16x32_bf16(af[m], bf[n], acc[m][n], 0, 0, 0);
    __syncthreads();
  }

  int row0 = bm * 128 + wr * 64;
  int col0 = bn * 128 + wc * 64;
#pragma unroll
  for (int n = 0; n < 4; n++) {
    int g = col0 + n * 16;            // group base column (uniform)
    int h = g / 192;
    int w = g % 192;                  // 16-col group never straddles a 192 boundary
    float bv = bias[g + l15];
    if (w < 128) {                    // Q or K -> qk[row][h*128 + w]
      int colq = h * 128 + w + l15;
#pragma unroll
      for (int m = 0; m < 4; m++)
#pragma unroll
        for (int r = 0; r < 4; r++) {
          int row = row0 + m * 16 + lh * 4 + r;
          qk[(size_t)row * QKLD + colq] = f2bf(acc[m][n][r] + bv);
        }
    } else {                          // V -> vT[bh][d][s]  (transposed store)
      int d = w - 128 + l15;
#pragma unroll
      for (int m = 0; m < 4; m++) {
        int row = row0 + m * 16 + lh * 4;
        int bb = row >> 11, s = row & 2047;
        u16x4 pk;
#pragma unroll
        for (int r = 0; r < 4; r++) pk[r] = f2bf(acc[m][n][r] + bv);
        *reinterpret_cast<u16x4*>(&vT[((size_t)(bb * 16 + h) * 64 + d) * S_ + s]) = pk;
      }
    }
  }
}

// ---------------- causal flash attention: 32x32 MFMA, 2 waves x 32 q ----------------
// Block: QB=64 (2 waves), KVBLK=64, reg-staged dbuf, 1 barrier/iter.
// Swapped everything: S^T = mfma(K, Q) -> lane owns q=lane&31, 16 k per n-tile.
// O^T = mfma(V^T, P^T-read). LDS rows are 128B, XOR-swizzled.

__device__ __forceinline__ int swz(int row, int col) {    // -> BYTE offset
  int byte = (row << 7) + (col << 1);
  return byte ^ ((((row & 7) ^ ((row >> 3) & 7)) << 4));
}
__device__ __forceinline__ unsigned short* ldsp(unsigned short* base, int byteoff) {
  return (unsigned short*)((char*)base + byteoff);
}

struct Stage { u16x8 k[4]; u16x8 v[4]; };

__device__ __forceinline__ void stage_load(Stage& st, const unsigned short* kb,
                                           const unsigned short* vb, int tid) {
#pragma unroll
  for (int i = 0; i < 4; i++) {
    int c = tid + i * 128;
    int row = c >> 3, col = (c & 7) * 8;
    st.k[i] = *reinterpret_cast<const u16x8*>(kb + (size_t)row * QKLD + col);
    st.v[i] = *reinterpret_cast<const u16x8*>(vb + (size_t)row * S_ + col);
  }
}
__device__ __forceinline__ void stage_write(const Stage& st, unsigned short* sk,
                                            unsigned short* sv, int tid) {
#pragma unroll
  for (int i = 0; i < 4; i++) {
    int c = tid + i * 128;
    int row = c >> 3, col = (c & 7) * 8;
    *reinterpret_cast<u16x8*>(ldsp(sk, swz(row, col))) = st.k[i];
    *reinterpret_cast<u16x8*>(ldsp(sv, swz(row, col))) = st.v[i];
  }
}

__global__ __launch_bounds__(128, 2) void attn_kernel(const unsigned short* __restrict__ qk,
                                                      const unsigned short* __restrict__ vT,
                                                      float* __restrict__ out) {
  __shared__ unsigned short sK[2][4096];     // [64 k][64 d] swizzled
  __shared__ unsigned short sVt[2][4096];    // [64 d][64 k] swizzled
  __shared__ unsigned short sPT[2][2048];    // per-wave [32 q][64 k] swizzled

  // strip mapping: any 4 consecutive (or stride-256) blocks sum to 66 iters
  const int lin = blockIdx.x;
  const int j = lin & 3;
  const int g = lin >> 2;
  const int bh = g >> 3;
  const int r8 = g & 7;
  const int qt = (j == 0) ? r8 : (j == 1) ? 15 - r8 : (j == 2) ? 16 + r8 : 31 - r8;

  const int b = bh >> 4, h = bh & 15;
  const int tid = threadIdx.x;
  const int wid = tid >> 6, lane = tid & 63;
  const int l31 = lane & 31, hi = lane >> 5;
  const int rowb = b * S_;

  const unsigned short* kbase = qk + (size_t)rowb * QKLD + h * 128 + 64;
  const unsigned short* vbase = vT + (size_t)bh * 64 * S_;
  unsigned short* myP = sPT[wid];

  const int ktiles = qt + 1;
  const int qrow = qt * 64 + wid * 32 + l31;   // this lane's q-row

  // Q B-frags: col=q=lane&31, k-dim elems (lane>>5)*8+j ; 4 d-steps of 16
  short8 qf[4];
#pragma unroll
  for (int st = 0; st < 4; st++)
    qf[st] = *reinterpret_cast<const short8*>(
        qk + (size_t)(rowb + qrow) * QKLD + h * 128 + st * 16 + hi * 8);

  float m_s = -1e30f, l_s = 0.f;
  f32x16 o0, o1;
#pragma unroll
  for (int r = 0; r < 16; r++) { o0[r] = 0.f; o1[r] = 0.f; }

  Stage st;
  stage_load(st, kbase, vbase, tid);
  stage_write(st, sK[0], sVt[0], tid);
  __syncthreads();

  for (int t = 0; t < ktiles; t++) {
    const int cur = t & 1;
    if (t + 1 < ktiles)
      stage_load(st, kbase + (size_t)(t + 1) * 64 * QKLD, vbase + (t + 1) * 64, tid);

    const bool diag = (t == qt);
    // S^T tiles: s0 = k-rows 0..31, s1 = 32..63 (of this KV tile)
    f32x16 s0, s1;
    __builtin_amdgcn_s_setprio(1);
    {
      f32x16 a;
#pragma unroll
      for (int r = 0; r < 16; r++) a[r] = 0.f;
#pragma unroll
      for (int stp = 0; stp < 4; stp++) {
        short8 kf = *reinterpret_cast<const short8*>(
            ldsp((unsigned short*)sK[cur], swz(l31, stp * 16 + hi * 8)));
        a = __builtin_amdgcn_mfma_f32_32x32x16_bf16(kf, qf[stp], a, 0, 0, 0);
      }
      s0 = a;
    }
    if (!(diag && wid == 0)) {
      f32x16 a;
#pragma unroll
      for (int r = 0; r < 16; r++) a[r] = 0.f;
#pragma unroll
      for (int stp = 0; stp < 4; stp++) {
        short8 kf = *reinterpret_cast<const short8*>(
            ldsp((unsigned short*)sK[cur], swz(32 + l31, stp * 16 + hi * 8)));
        a = __builtin_amdgcn_mfma_f32_32x32x16_bf16(kf, qf[stp], a, 0, 0, 0);
      }
      s1 = a;
    } else {
#pragma unroll
      for (int r = 0; r < 16; r++) s1[r] = -1e30f;
    }
    __builtin_amdgcn_s_setprio(0);

    if (diag) {
      const int kb0 = t * 64;
      if (wid == 0) {
#pragma unroll
        for (int r = 0; r < 16; r++) {
          int kg = kb0 + (r & 3) + 8 * (r >> 2) + 4 * hi;
          if (kg > qrow) s0[r] = -1e30f;
        }
      } else {
#pragma unroll
        for (int r = 0; r < 16; r++) {
          int kg = kb0 + 32 + (r & 3) + 8 * (r >> 2) + 4 * hi;
          if (kg > qrow) s1[r] = -1e30f;
        }
      }
    }

    // lane-local softmax over 32 k-values (+1 shfl for the hi-half)
    float mx = s0[0];
#pragma unroll
    for (int r = 1; r < 16; r++) mx = fmaxf(mx, s0[r]);
#pragma unroll
    for (int r = 0; r < 16; r++) mx = fmaxf(mx, s1[r]);
    mx = fmaxf(mx, __shfl_xor(mx, 32));

    if (!__all(mx <= m_s)) {          // defer-max
      float mnew = fmaxf(m_s, mx);
      float scl = fast_exp2((m_s - mnew) * C_SCALE);
      m_s = mnew;
      l_s *= scl;
#pragma unroll
      for (int r = 0; r < 16; r++) { o0[r] *= scl; o1[r] *= scl; }
    }

    const float mC = m_s * C_SCALE;
    float ps = 0.f;
#pragma unroll
    for (int r = 0; r < 16; r++) {
      s0[r] = fast_exp2(fmaf(s0[r], C_SCALE, -mC));
      ps += s0[r];
    }
#pragma unroll
    for (int r = 0; r < 16; r++) {
      s1[r] = fast_exp2(fmaf(s1[r], C_SCALE, -mC));
      ps += s1[r];
    }
    ps += __shfl_xor(ps, 32);
    l_s += ps;

    // P^T store: [q=l31][k], 4 consecutive k per reg-group (trunc pack)
#pragma unroll
    for (int rg = 0; rg < 4; rg++) {
      u16x4 p0, p1;
#pragma unroll
      for (int i = 0; i < 4; i++) {
        p0[i] = f2bf_trunc(s0[rg * 4 + i]);
        p1[i] = f2bf_trunc(s1[rg * 4 + i]);
      }
      *reinterpret_cast<u16x4*>(ldsp(myP, swz(l31, rg * 8 + hi * 4))) = p0;
      *reinterpret_cast<u16x4*>(ldsp(myP, swz(l31, 32 + rg * 8 + hi * 4))) = p1;
    }

    // O^T += V^T * P : A = V^T (d rows), B = P^T rows read k-contiguous
    short8 pf[4];
#pragma unroll
    for (int ks = 0; ks < 4; ks++)
      pf[ks] = *reinterpret_cast<const short8*>(
          ldsp(myP, swz(l31, ks * 16 + hi * 8)));
    __builtin_amdgcn_s_setprio(1);
#pragma unroll
    for (int ks = 0; ks < 4; ks++) {
      short8 vf0 = *reinterpret_cast<const short8*>(
          ldsp((unsigned short*)sVt[cur], swz(l31, ks * 16 + hi * 8)));
      o0 = __builtin_amdgcn_mfma_f32_32x32x16_bf16(vf0, pf[ks], o0, 0, 0, 0);
      short8 vf1 = *reinterpret_cast<const short8*>(
          ldsp((unsigned short*)sVt[cur], swz(32 + l31, ks * 16 + hi * 8)));
      o1 = __builtin_amdgcn_mfma_f32_32x32x16_bf16(vf1, pf[ks], o1, 0, 0, 0);
    }
    __builtin_amdgcn_s_setprio(0);

    if (t + 1 < ktiles) {
      stage_write(st, sK[cur ^ 1], sVt[cur ^ 1], tid);
      __syncthreads();
    }
  }

  // epilogue: o[dt][r] = O[q=l31][d = dt*32 + 8*(r>>2) + 4*hi + (r&3)]
  float inv = 1.f / l_s;
  float* op = &out[(size_t)(rowb + qrow) * D_ + h * 64];
#pragma unroll
  for (int rg = 0; rg < 4; rg++) {
    f32x4 v0, v1;
#pragma unroll
    for (int i = 0; i < 4; i++) {
      v0[i] = o0[rg * 4 + i] * inv;
      v1[i] = o1[rg * 4 + i] * inv;
    }
    *reinterpret_cast<f32x4*>(&op[rg * 8 + hi * 4]) = v0;
    *reinterpret_cast<f32x4*>(&op[32 + rg * 8 + hi * 4]) = v1;
  }
}

extern "C" void kernel_launch(void* const* d_in, const int* in_sizes, int n_in,
                              void* d_out, int out_size, void* d_ws, size_t ws_size,
                              hipStream_t stream) {
  const float* x    = (const float*)d_in[0];
  const float* W    = (const float*)d_in[1];
  const float* bias = (const float*)d_in[2];
  float* out = (float*)d_out;
  char* ws = (char*)d_ws;
  unsigned short* xb  = (unsigned short*)(ws);                    // 8 MB
  unsigned short* wt  = (unsigned short*)(ws + (8u << 20));       // 6 MB
  unsigned short* qk  = (unsigned short*)(ws + (14u << 20));      // 16 MB
  unsigned short* vTb = (unsigned short*)(ws + (30u << 20));      // 8 MB

  conv_x_kernel<<<4096, 256, 0, stream>>>(x, xb);
  transpose_w_kernel<<<dim3(48, 16), 256, 0, stream>>>(W, wt);
  qkv_gemm_kernel<<<dim3(24, 32), 256, 0, stream>>>(xb, wt, bias, qk, vTb);
  attn_kernel<<<1024, 128, 0, stream>>>(qk, vTb, out);
}

// Round 5
// 111.534 us; speedup vs baseline: 2.4433x; 1.1109x over previous
//
#include <hip/hip_runtime.h>
#include <hip/hip_bf16.h>

typedef __attribute__((ext_vector_type(8))) short short8;
typedef __attribute__((ext_vector_type(8))) unsigned short u16x8;
typedef __attribute__((ext_vector_type(4))) unsigned short u16x4;
typedef __attribute__((ext_vector_type(4))) float f32x4;
typedef __attribute__((ext_vector_type(16))) float f32x16;

#define S_  2048
#define D_  1024
#define F3  3072
#define QKLD 2048                  // qk buffer: row s -> [h][q 64 | k 64]
#define LOG2E 1.4426950408889634f
#define C_SCALE (0.125f * LOG2E)   // 1/sqrt(64) folded into exp2

__device__ __forceinline__ unsigned short f2bf(float f) {
  unsigned int u = __builtin_bit_cast(unsigned int, f);
  u += 0x7fffu + ((u >> 16) & 1u);
  return (unsigned short)(u >> 16);
}
__device__ __forceinline__ unsigned short f2bf_trunc(float f) {
  return (unsigned short)(__builtin_bit_cast(unsigned int, f) >> 16);
}
__device__ __forceinline__ float fast_exp2(float x) {
  float r;
  asm("v_exp_f32 %0, %1" : "=v"(r) : "v"(x));
  return r;
}

// ---------------- x (f32) -> bf16 ----------------
__global__ __launch_bounds__(256) void conv_x_kernel(const float* __restrict__ x,
                                                     unsigned short* __restrict__ xb) {
  int i = (blockIdx.x * 256 + threadIdx.x) * 4;
  f32x4 v = *reinterpret_cast<const f32x4*>(&x[i]);
  u16x4 o;
  o[0] = f2bf(v[0]); o[1] = f2bf(v[1]); o[2] = f2bf(v[2]); o[3] = f2bf(v[3]);
  *reinterpret_cast<u16x4*>(&xb[i]) = o;
}

// ---------------- W [1024][3072] f32 -> Wt [3072][1024] bf16 ----------------
__global__ __launch_bounds__(256) void transpose_w_kernel(const float* __restrict__ W,
                                                          unsigned short* __restrict__ Wt) {
  __shared__ float tile[64][65];
  int nt = blockIdx.x;
  int kt = blockIdx.y;
  int tid = threadIdx.x;
#pragma unroll
  for (int i = 0; i < 16; i++) {
    int idx = tid + i * 256;
    int r = idx >> 6, c = idx & 63;
    tile[r][c] = W[(size_t)(kt * 64 + r) * F3 + nt * 64 + c];
  }
  __syncthreads();
#pragma unroll
  for (int i = 0; i < 16; i++) {
    int idx = tid + i * 256;
    int rn = idx >> 6, ck = idx & 63;
    Wt[(size_t)(nt * 64 + rn) * D_ + kt * 64 + ck] = f2bf(tile[ck][rn]);
  }
}

// ------- GEMM (m97 structure): global_load_lds staging, linear LDS, 2-barrier loop ---
__global__ __launch_bounds__(256) void qkv_gemm_kernel(const unsigned short* __restrict__ A,
                                                       const unsigned short* __restrict__ Bt,
                                                       const float* __restrict__ bias,
                                                       unsigned short* __restrict__ qk,
                                                       unsigned short* __restrict__ vT) {
  constexpr int K = D_;
  __shared__ unsigned short sA[128 * 32];
  __shared__ unsigned short sB[128 * 32];
  int bn = blockIdx.x, bm = blockIdx.y;
  int tid = threadIdx.x;
  int wid = tid >> 6, lane = tid & 63;
  int wr = wid >> 1, wc = wid & 1;
  int lh = lane >> 4, l15 = lane & 15;
  f32x4 acc[4][4] = {};

  // chunk t = tid covers LDS bytes t*16.. (row=t>>2, col elems (t&3)*8); wave-linear dest
  const int row1 = tid >> 2;            // 0..63
  const int colb = (tid & 3) * 8;
  const unsigned short* ga = &A[(size_t)(bm * 128 + row1) * K + colb];
  const unsigned short* gb = &Bt[(size_t)(bn * 128 + row1) * K + colb];
  unsigned short* la = &sA[wid * 512];  // wave-uniform base (+ lane*16B implied)
  unsigned short* lb = &sB[wid * 512];

  for (int k0 = 0; k0 < K; k0 += 32) {
    __builtin_amdgcn_global_load_lds((const unsigned int*)(ga + k0), (unsigned int*)la, 16, 0, 0);
    __builtin_amdgcn_global_load_lds((const unsigned int*)(ga + (size_t)64 * K + k0),
                                     (unsigned int*)(la + 2048), 16, 0, 0);
    __builtin_amdgcn_global_load_lds((const unsigned int*)(gb + k0), (unsigned int*)lb, 16, 0, 0);
    __builtin_amdgcn_global_load_lds((const unsigned int*)(gb + (size_t)64 * K + k0),
                                     (unsigned int*)(lb + 2048), 16, 0, 0);
    asm volatile("s_waitcnt vmcnt(0)" ::: "memory");
    __syncthreads();

    short8 af[4], bf[4];
#pragma unroll
    for (int m = 0; m < 4; m++)
      af[m] = *reinterpret_cast<const short8*>(&sA[(wr * 64 + m * 16 + l15) * 32 + lh * 8]);
#pragma unroll
    for (int n = 0; n < 4; n++)
      bf[n] = *reinterpret_cast<const short8*>(&sB[(wc * 64 + n * 16 + l15) * 32 + lh * 8]);
#pragma unroll
    for (int m = 0; m < 4; m++)
#pragma unroll
      for (int n = 0; n < 4; n++)
        acc[m][n] = __builtin_amdgcn_mfma_f32_16x16x32_bf16(af[m], bf[n], acc[m][n], 0, 0, 0);
    __syncthreads();
  }

  int row0 = bm * 128 + wr * 64;
  int col0 = bn * 128 + wc * 64;
#pragma unroll
  for (int n = 0; n < 4; n++) {
    int g = col0 + n * 16;            // group base column (uniform)
    int h = g / 192;
    int w = g % 192;                  // 16-col group never straddles a 192 boundary
    float bv = bias[g + l15];
    if (w < 128) {                    // Q or K -> qk[row][h*128 + w]
      int colq = h * 128 + w + l15;
#pragma unroll
      for (int m = 0; m < 4; m++)
#pragma unroll
        for (int r = 0; r < 4; r++) {
          int row = row0 + m * 16 + lh * 4 + r;
          qk[(size_t)row * QKLD + colq] = f2bf(acc[m][n][r] + bv);
        }
    } else {                          // V -> vT[bh][d][s]  (transposed store)
      int d = w - 128 + l15;
#pragma unroll
      for (int m = 0; m < 4; m++) {
        int row = row0 + m * 16 + lh * 4;
        int bb = row >> 11, s = row & 2047;
        u16x4 pk;
#pragma unroll
        for (int r = 0; r < 4; r++) pk[r] = f2bf(acc[m][n][r] + bv);
        *reinterpret_cast<u16x4*>(&vT[((size_t)(bb * 16 + h) * 64 + d) * S_ + s]) = pk;
      }
    }
  }
}

// ---------------- causal flash attention: 32x32 MFMA, 2 waves x 32 q ----------------
__device__ __forceinline__ int swz(int row, int col) {    // -> BYTE offset
  int byte = (row << 7) + (col << 1);
  return byte ^ ((((row & 7) ^ ((row >> 3) & 7)) << 4));
}
__device__ __forceinline__ unsigned short* ldsp(unsigned short* base, int byteoff) {
  return (unsigned short*)((char*)base + byteoff);
}

struct Stage { u16x8 k[4]; u16x8 v[4]; };

__device__ __forceinline__ void stage_load(Stage& st, const unsigned short* kb,
                                           const unsigned short* vb, int tid) {
#pragma unroll
  for (int i = 0; i < 4; i++) {
    int c = tid + i * 128;
    int row = c >> 3, col = (c & 7) * 8;
    st.k[i] = *reinterpret_cast<const u16x8*>(kb + (size_t)row * QKLD + col);
    st.v[i] = *reinterpret_cast<const u16x8*>(vb + (size_t)row * S_ + col);
  }
}
__device__ __forceinline__ void stage_write(const Stage& st, unsigned short* sk,
                                            unsigned short* sv, int tid) {
#pragma unroll
  for (int i = 0; i < 4; i++) {
    int c = tid + i * 128;
    int row = c >> 3, col = (c & 7) * 8;
    *reinterpret_cast<u16x8*>(ldsp(sk, swz(row, col))) = st.k[i];
    *reinterpret_cast<u16x8*>(ldsp(sv, swz(row, col))) = st.v[i];
  }
}

__global__ __launch_bounds__(128, 2) void attn_kernel(const unsigned short* __restrict__ qk,
                                                      const unsigned short* __restrict__ vT,
                                                      float* __restrict__ out) {
  __shared__ unsigned short sK[2][4096];     // [64 k][64 d] swizzled
  __shared__ unsigned short sVt[2][4096];    // [64 d][64 k] swizzled
  __shared__ unsigned short sPT[2][2048];    // per-wave [32 q][64 k] swizzled

  // Strip map balanced for stride-256 co-residency (XCD round-robin):
  // CU hosts {lin, lin+256, lin+512, lin+768} -> qt {r,15-r,16+r,31-r}, sum(ktiles)=66,
  // same bh (L2 locality for K/V).
  const int lin = blockIdx.x;
  const int j = lin >> 8;
  const int r8 = (lin >> 5) & 7;
  const int bh = lin & 31;
  const int qt = (j == 0) ? r8 : (j == 1) ? 15 - r8 : (j == 2) ? 16 + r8 : 31 - r8;

  const int b = bh >> 4, h = bh & 15;
  const int tid = threadIdx.x;
  const int wid = tid >> 6, lane = tid & 63;
  const int l31 = lane & 31, hi = lane >> 5;
  const int rowb = b * S_;

  const unsigned short* kbase = qk + (size_t)rowb * QKLD + h * 128 + 64;
  const unsigned short* vbase = vT + (size_t)bh * 64 * S_;
  unsigned short* myP = sPT[wid];

  const int ktiles = qt + 1;
  const int qrow = qt * 64 + wid * 32 + l31;   // this lane's q-row

  short8 qf[4];
#pragma unroll
  for (int st = 0; st < 4; st++)
    qf[st] = *reinterpret_cast<const short8*>(
        qk + (size_t)(rowb + qrow) * QKLD + h * 128 + st * 16 + hi * 8);

  float m_s = -1e30f, l_s = 0.f;
  f32x16 o0, o1;
#pragma unroll
  for (int r = 0; r < 16; r++) { o0[r] = 0.f; o1[r] = 0.f; }

  Stage st;
  stage_load(st, kbase, vbase, tid);
  stage_write(st, sK[0], sVt[0], tid);
  __syncthreads();

  for (int t = 0; t < ktiles; t++) {
    const int cur = t & 1;
    if (t + 1 < ktiles)
      stage_load(st, kbase + (size_t)(t + 1) * 64 * QKLD, vbase + (t + 1) * 64, tid);

    const bool diag = (t == qt);
    f32x16 s0, s1;
    __builtin_amdgcn_s_setprio(1);
    {
      f32x16 a;
#pragma unroll
      for (int r = 0; r < 16; r++) a[r] = 0.f;
#pragma unroll
      for (int stp = 0; stp < 4; stp++) {
        short8 kf = *reinterpret_cast<const short8*>(
            ldsp((unsigned short*)sK[cur], swz(l31, stp * 16 + hi * 8)));
        a = __builtin_amdgcn_mfma_f32_32x32x16_bf16(kf, qf[stp], a, 0, 0, 0);
      }
      s0 = a;
    }
    if (!(diag && wid == 0)) {
      f32x16 a;
#pragma unroll
      for (int r = 0; r < 16; r++) a[r] = 0.f;
#pragma unroll
      for (int stp = 0; stp < 4; stp++) {
        short8 kf = *reinterpret_cast<const short8*>(
            ldsp((unsigned short*)sK[cur], swz(32 + l31, stp * 16 + hi * 8)));
        a = __builtin_amdgcn_mfma_f32_32x32x16_bf16(kf, qf[stp], a, 0, 0, 0);
      }
      s1 = a;
    } else {
#pragma unroll
      for (int r = 0; r < 16; r++) s1[r] = -1e30f;
    }
    __builtin_amdgcn_s_setprio(0);

    if (diag) {
      const int kb0 = t * 64;
      if (wid == 0) {
#pragma unroll
        for (int r = 0; r < 16; r++) {
          int kg = kb0 + (r & 3) + 8 * (r >> 2) + 4 * hi;
          if (kg > qrow) s0[r] = -1e30f;
        }
      } else {
#pragma unroll
        for (int r = 0; r < 16; r++) {
          int kg = kb0 + 32 + (r & 3) + 8 * (r >> 2) + 4 * hi;
          if (kg > qrow) s1[r] = -1e30f;
        }
      }
    }

    float mx = s0[0];
#pragma unroll
    for (int r = 1; r < 16; r++) mx = fmaxf(mx, s0[r]);
#pragma unroll
    for (int r = 0; r < 16; r++) mx = fmaxf(mx, s1[r]);
    mx = fmaxf(mx, __shfl_xor(mx, 32));

    if (!__all(mx <= m_s)) {          // defer-max
      float mnew = fmaxf(m_s, mx);
      float scl = fast_exp2((m_s - mnew) * C_SCALE);
      m_s = mnew;
      l_s *= scl;
#pragma unroll
      for (int r = 0; r < 16; r++) { o0[r] *= scl; o1[r] *= scl; }
    }

    const float mC = m_s * C_SCALE;
    float ps = 0.f;
#pragma unroll
    for (int r = 0; r < 16; r++) {
      s0[r] = fast_exp2(fmaf(s0[r], C_SCALE, -mC));
      ps += s0[r];
    }
#pragma unroll
    for (int r = 0; r < 16; r++) {
      s1[r] = fast_exp2(fmaf(s1[r], C_SCALE, -mC));
      ps += s1[r];
    }
    ps += __shfl_xor(ps, 32);
    l_s += ps;

#pragma unroll
    for (int rg = 0; rg < 4; rg++) {
      u16x4 p0, p1;
#pragma unroll
      for (int i = 0; i < 4; i++) {
        p0[i] = f2bf_trunc(s0[rg * 4 + i]);
        p1[i] = f2bf_trunc(s1[rg * 4 + i]);
      }
      *reinterpret_cast<u16x4*>(ldsp(myP, swz(l31, rg * 8 + hi * 4))) = p0;
      *reinterpret_cast<u16x4*>(ldsp(myP, swz(l31, 32 + rg * 8 + hi * 4))) = p1;
    }

    short8 pf[4];
#pragma unroll
    for (int ks = 0; ks < 4; ks++)
      pf[ks] = *reinterpret_cast<const short8*>(
          ldsp(myP, swz(l31, ks * 16 + hi * 8)));
    __builtin_amdgcn_s_setprio(1);
#pragma unroll
    for (int ks = 0; ks < 4; ks++) {
      short8 vf0 = *reinterpret_cast<const short8*>(
          ldsp((unsigned short*)sVt[cur], swz(l31, ks * 16 + hi * 8)));
      o0 = __builtin_amdgcn_mfma_f32_32x32x16_bf16(vf0, pf[ks], o0, 0, 0, 0);
      short8 vf1 = *reinterpret_cast<const short8*>(
          ldsp((unsigned short*)sVt[cur], swz(32 + l31, ks * 16 + hi * 8)));
      o1 = __builtin_amdgcn_mfma_f32_32x32x16_bf16(vf1, pf[ks], o1, 0, 0, 0);
    }
    __builtin_amdgcn_s_setprio(0);

    if (t + 1 < ktiles) {
      stage_write(st, sK[cur ^ 1], sVt[cur ^ 1], tid);
      __syncthreads();
    }
  }

  float inv = 1.f / l_s;
  float* op = &out[(size_t)(rowb + qrow) * D_ + h * 64];
#pragma unroll
  for (int rg = 0; rg < 4; rg++) {
    f32x4 v0, v1;
#pragma unroll
    for (int i = 0; i < 4; i++) {
      v0[i] = o0[rg * 4 + i] * inv;
      v1[i] = o1[rg * 4 + i] * inv;
    }
    *reinterpret_cast<f32x4*>(&op[rg * 8 + hi * 4]) = v0;
    *reinterpret_cast<f32x4*>(&op[32 + rg * 8 + hi * 4]) = v1;
  }
}

extern "C" void kernel_launch(void* const* d_in, const int* in_sizes, int n_in,
                              void* d_out, int out_size, void* d_ws, size_t ws_size,
                              hipStream_t stream) {
  const float* x    = (const float*)d_in[0];
  const float* W    = (const float*)d_in[1];
  const float* bias = (const float*)d_in[2];
  float* out = (float*)d_out;
  char* ws = (char*)d_ws;
  unsigned short* xb  = (unsigned short*)(ws);                    // 8 MB
  unsigned short* wt  = (unsigned short*)(ws + (8u << 20));       // 6 MB
  unsigned short* qk  = (unsigned short*)(ws + (14u << 20));      // 16 MB
  unsigned short* vTb = (unsigned short*)(ws + (30u << 20));      // 8 MB

  conv_x_kernel<<<4096, 256, 0, stream>>>(x, xb);
  transpose_w_kernel<<<dim3(48, 16), 256, 0, stream>>>(W, wt);
  qkv_gemm_kernel<<<dim3(24, 32), 256, 0, stream>>>(xb, wt, bias, qk, vTb);
  attn_kernel<<<1024, 128, 0, stream>>>(qk, vTb, out);
}

// Round 7
// 108.958 us; speedup vs baseline: 2.5011x; 1.0236x over previous
//
#include <hip/hip_runtime.h>
#include <hip/hip_bf16.h>

typedef __attribute__((ext_vector_type(8))) short short8;
typedef __attribute__((ext_vector_type(8))) unsigned short u16x8;
typedef __attribute__((ext_vector_type(4))) unsigned short u16x4;
typedef __attribute__((ext_vector_type(4))) float f32x4;
typedef __attribute__((ext_vector_type(16))) float f32x16;

#define S_  2048
#define D_  1024
#define F3  3072
#define QKLD 2048                  // qk buffer: row s -> [h][q 64 | k 64]
#define LOG2E 1.4426950408889634f
#define C_SCALE (0.125f * LOG2E)   // 1/sqrt(64) folded into exp2

__device__ __forceinline__ unsigned short f2bf(float f) {
  unsigned int u = __builtin_bit_cast(unsigned int, f);
  u += 0x7fffu + ((u >> 16) & 1u);
  return (unsigned short)(u >> 16);
}
__device__ __forceinline__ unsigned short f2bf_trunc(float f) {
  return (unsigned short)(__builtin_bit_cast(unsigned int, f) >> 16);
}
__device__ __forceinline__ float fast_exp2(float x) {
  float r;
  asm("v_exp_f32 %0, %1" : "=v"(r) : "v"(x));
  return r;
}

// XOR swizzle for 128B LDS rows (8 x 16B chunks), 3-bit key
__device__ __forceinline__ int swz(int row, int col) {    // -> BYTE offset
  int byte = (row << 7) + (col << 1);
  return byte ^ ((((row & 7) ^ ((row >> 3) & 7)) << 4));
}
__device__ __forceinline__ unsigned short* ldsp(unsigned short* base, int byteoff) {
  return (unsigned short*)((char*)base + byteoff);
}

// ---------------- x (f32) -> bf16 ----------------
__global__ __launch_bounds__(256) void conv_x_kernel(const float* __restrict__ x,
                                                     unsigned short* __restrict__ xb) {
  int i = (blockIdx.x * 256 + threadIdx.x) * 4;
  f32x4 v = *reinterpret_cast<const f32x4*>(&x[i]);
  u16x4 o;
  o[0] = f2bf(v[0]); o[1] = f2bf(v[1]); o[2] = f2bf(v[2]); o[3] = f2bf(v[3]);
  *reinterpret_cast<u16x4*>(&xb[i]) = o;
}

// ---------------- W [1024][3072] f32 -> Wt [3072][1024] bf16 ----------------
__global__ __launch_bounds__(256) void transpose_w_kernel(const float* __restrict__ W,
                                                          unsigned short* __restrict__ Wt) {
  __shared__ float tile[64][65];
  int nt = blockIdx.x;
  int kt = blockIdx.y;
  int tid = threadIdx.x;
#pragma unroll
  for (int i = 0; i < 16; i++) {
    int idx = tid + i * 256;
    int r = idx >> 6, c = idx & 63;
    tile[r][c] = W[(size_t)(kt * 64 + r) * F3 + nt * 64 + c];
  }
  __syncthreads();
#pragma unroll
  for (int i = 0; i < 16; i++) {
    int idx = tid + i * 256;
    int rn = idx >> 6, ck = idx & 63;
    Wt[(size_t)(nt * 64 + rn) * D_ + kt * 64 + ck] = f2bf(tile[ck][rn]);
  }
}

// ------- GEMM: gload_lds staging + 64B-row XOR swizzle (both sides), split epilogue --
__global__ __launch_bounds__(256) void qkv_gemm_kernel(const unsigned short* __restrict__ A,
                                                       const unsigned short* __restrict__ Bt,
                                                       const float* __restrict__ bias,
                                                       unsigned short* __restrict__ qk,
                                                       unsigned short* __restrict__ vT) {
  constexpr int K = D_;
  __shared__ unsigned short sA[128 * 32];
  __shared__ unsigned short sB[128 * 32];
  int bn = blockIdx.x, bm = blockIdx.y;
  int tid = threadIdx.x;
  int wid = tid >> 6, lane = tid & 63;
  int wr = wid >> 1, wc = wid & 1;
  int lh = lane >> 4, l15 = lane & 15;
  f32x4 acc[4][4] = {};

  // staging: chunk t=tid -> LDS linear (row=t>>2, blk=t&3); source col pre-swizzled
  const int row1 = tid >> 2;            // 0..63 (key(row1+64)==key(row1))
  const int skey = (row1 ^ (row1 >> 2)) & 3;
  const int colb = ((tid & 3) ^ skey) * 8;
  const unsigned short* ga = &A[(size_t)(bm * 128 + row1) * K + colb];
  const unsigned short* gb = &Bt[(size_t)(bn * 128 + row1) * K + colb];
  unsigned short* la = &sA[wid * 512];  // wave-uniform base (+ lane*16B implied)
  unsigned short* lb = &sB[wid * 512];

  for (int k0 = 0; k0 < K; k0 += 32) {
    __builtin_amdgcn_global_load_lds((const unsigned int*)(ga + k0), (unsigned int*)la, 16, 0, 0);
    __builtin_amdgcn_global_load_lds((const unsigned int*)(ga + (size_t)64 * K + k0),
                                     (unsigned int*)(la + 2048), 16, 0, 0);
    __builtin_amdgcn_global_load_lds((const unsigned int*)(gb + k0), (unsigned int*)lb, 16, 0, 0);
    __builtin_amdgcn_global_load_lds((const unsigned int*)(gb + (size_t)64 * K + k0),
                                     (unsigned int*)(lb + 2048), 16, 0, 0);
    asm volatile("s_waitcnt vmcnt(0)" ::: "memory");
    __syncthreads();

    short8 af[4], bf[4];
#pragma unroll
    for (int m = 0; m < 4; m++) {
      int ar = wr * 64 + m * 16 + l15;
      int ab = (ar * 64 + lh * 16) ^ (((ar ^ (ar >> 2)) & 3) << 4);
      af[m] = *reinterpret_cast<const short8*>((const char*)sA + ab);
    }
#pragma unroll
    for (int n = 0; n < 4; n++) {
      int br = wc * 64 + n * 16 + l15;
      int bb = (br * 64 + lh * 16) ^ (((br ^ (br >> 2)) & 3) << 4);
      bf[n] = *reinterpret_cast<const short8*>((const char*)sB + bb);
    }
#pragma unroll
    for (int m = 0; m < 4; m++)
#pragma unroll
      for (int n = 0; n < 4; n++)
        acc[m][n] = __builtin_amdgcn_mfma_f32_16x16x32_bf16(af[m], bf[n], acc[m][n], 0, 0, 0);
    __syncthreads();
  }

  int row0 = bm * 128 + wr * 64;
  int col0 = bn * 128 + wc * 64;
  const int bn3 = bn % 3;
  const int vside = (bn3 == 1) ? 0 : (bn3 == 2) ? 1 : -1;

  if (wc == vside) {
    // V epilogue: transpose 64s x 64d via own LDS half, then coalesced 128B-row stores
    unsigned short* tile = wr ? sB : sA;          // 8KB = [64 d][64 s], swizzled rows
    const int h = col0 / 192;                     // group base has w==128 -> d = 0..63
#pragma unroll
    for (int n = 0; n < 4; n++) {
      int d = n * 16 + l15;
      float bv = bias[col0 + n * 16 + l15];
#pragma unroll
      for (int m = 0; m < 4; m++) {
        u16x4 pk;
#pragma unroll
        for (int r = 0; r < 4; r++) pk[r] = f2bf(acc[m][n][r] + bv);
        *reinterpret_cast<u16x4*>(ldsp(tile, swz(d, m * 16 + lh * 4))) = pk;
      }
    }
    const int bbat = row0 >> 11, s0g = row0 & 2047;
    unsigned short* vrow = &vT[(size_t)(bbat * 16 + h) * 64 * S_ + s0g];
#pragma unroll
    for (int i = 0; i < 8; i++) {
      int c = lane + i * 64;
      int rrow = c >> 3, blk = c & 7;
      short8 v = *reinterpret_cast<const short8*>(ldsp(tile, swz(rrow, blk * 8)));
      *reinterpret_cast<short8*>(&vrow[(size_t)rrow * S_ + blk * 8]) = v;
    }
  } else {
    // Q/K epilogue (all 4 n-groups have w<128 on this side)
#pragma unroll
    for (int n = 0; n < 4; n++) {
      int g = col0 + n * 16;
      int h = g / 192;
      int w = g % 192;
      float bv = bias[g + l15];
      int colq = h * 128 + w + l15;
#pragma unroll
      for (int m = 0; m < 4; m++)
#pragma unroll
        for (int r = 0; r < 4; r++) {
          int row = row0 + m * 16 + lh * 4 + r;
          qk[(size_t)row * QKLD + colq] = f2bf(acc[m][n][r] + bv);
        }
    }
  }
}

// ---------------- causal flash attention (R4 version, verbatim known-good) ----------
struct Stage { u16x8 k[4]; u16x8 v[4]; };

__device__ __forceinline__ void stage_load(Stage& st, const unsigned short* kb,
                                           const unsigned short* vb, int tid) {
#pragma unroll
  for (int i = 0; i < 4; i++) {
    int c = tid + i * 128;
    int row = c >> 3, col = (c & 7) * 8;
    st.k[i] = *reinterpret_cast<const u16x8*>(kb + (size_t)row * QKLD + col);
    st.v[i] = *reinterpret_cast<const u16x8*>(vb + (size_t)row * S_ + col);
  }
}
__device__ __forceinline__ void stage_write(const Stage& st, unsigned short* sk,
                                            unsigned short* sv, int tid) {
#pragma unroll
  for (int i = 0; i < 4; i++) {
    int c = tid + i * 128;
    int row = c >> 3, col = (c & 7) * 8;
    *reinterpret_cast<u16x8*>(ldsp(sk, swz(row, col))) = st.k[i];
    *reinterpret_cast<u16x8*>(ldsp(sv, swz(row, col))) = st.v[i];
  }
}

__global__ __launch_bounds__(128, 2) void attn_kernel(const unsigned short* __restrict__ qk,
                                                      const unsigned short* __restrict__ vT,
                                                      float* __restrict__ out) {
  __shared__ unsigned short sK[2][4096];     // [64 k][64 d] swizzled
  __shared__ unsigned short sVt[2][4096];    // [64 d][64 k] swizzled
  __shared__ unsigned short sPT[2][2048];    // per-wave [32 q][64 k] swizzled

  // Strip map balanced for stride-256 co-residency (XCD round-robin):
  // CU hosts {lin, lin+256, lin+512, lin+768} -> qt {r,15-r,16+r,31-r}, sum=66 iters,
  // same bh (L2 locality for K/V).
  const int lin = blockIdx.x;
  const int j = lin >> 8;
  const int r8 = (lin >> 5) & 7;
  const int bh = lin & 31;
  const int qt = (j == 0) ? r8 : (j == 1) ? 15 - r8 : (j == 2) ? 16 + r8 : 31 - r8;

  const int b = bh >> 4, h = bh & 15;
  const int tid = threadIdx.x;
  const int wid = tid >> 6, lane = tid & 63;
  const int l31 = lane & 31, hi = lane >> 5;
  const int rowb = b * S_;

  const unsigned short* kbase = qk + (size_t)rowb * QKLD + h * 128 + 64;
  const unsigned short* vbase = vT + (size_t)bh * 64 * S_;
  unsigned short* myP = sPT[wid];

  const int ktiles = qt + 1;
  const int qrow = qt * 64 + wid * 32 + l31;   // this lane's q-row

  short8 qf[4];
#pragma unroll
  for (int st = 0; st < 4; st++)
    qf[st] = *reinterpret_cast<const short8*>(
        qk + (size_t)(rowb + qrow) * QKLD + h * 128 + st * 16 + hi * 8);

  float m_s = -1e30f, l_s = 0.f;
  f32x16 o0, o1;
#pragma unroll
  for (int r = 0; r < 16; r++) { o0[r] = 0.f; o1[r] = 0.f; }

  Stage st;
  stage_load(st, kbase, vbase, tid);
  stage_write(st, sK[0], sVt[0], tid);
  __syncthreads();

  for (int t = 0; t < ktiles; t++) {
    const int cur = t & 1;
    if (t + 1 < ktiles)
      stage_load(st, kbase + (size_t)(t + 1) * 64 * QKLD, vbase + (t + 1) * 64, tid);

    const bool diag = (t == qt);
    f32x16 s0, s1;
    __builtin_amdgcn_s_setprio(1);
    {
      f32x16 a;
#pragma unroll
      for (int r = 0; r < 16; r++) a[r] = 0.f;
#pragma unroll
      for (int stp = 0; stp < 4; stp++) {
        short8 kf = *reinterpret_cast<const short8*>(
            ldsp((unsigned short*)sK[cur], swz(l31, stp * 16 + hi * 8)));
        a = __builtin_amdgcn_mfma_f32_32x32x16_bf16(kf, qf[stp], a, 0, 0, 0);
      }
      s0 = a;
    }
    if (!(diag && wid == 0)) {
      f32x16 a;
#pragma unroll
      for (int r = 0; r < 16; r++) a[r] = 0.f;
#pragma unroll
      for (int stp = 0; stp < 4; stp++) {
        short8 kf = *reinterpret_cast<const short8*>(
            ldsp((unsigned short*)sK[cur], swz(32 + l31, stp * 16 + hi * 8)));
        a = __builtin_amdgcn_mfma_f32_32x32x16_bf16(kf, qf[stp], a, 0, 0, 0);
      }
      s1 = a;
    } else {
#pragma unroll
      for (int r = 0; r < 16; r++) s1[r] = -1e30f;
    }
    __builtin_amdgcn_s_setprio(0);

    if (diag) {
      const int kb0 = t * 64;
      if (wid == 0) {
#pragma unroll
        for (int r = 0; r < 16; r++) {
          int kg = kb0 + (r & 3) + 8 * (r >> 2) + 4 * hi;
          if (kg > qrow) s0[r] = -1e30f;
        }
      } else {
#pragma unroll
        for (int r = 0; r < 16; r++) {
          int kg = kb0 + 32 + (r & 3) + 8 * (r >> 2) + 4 * hi;
          if (kg > qrow) s1[r] = -1e30f;
        }
      }
    }

    float mx = s0[0];
#pragma unroll
    for (int r = 1; r < 16; r++) mx = fmaxf(mx, s0[r]);
#pragma unroll
    for (int r = 0; r < 16; r++) mx = fmaxf(mx, s1[r]);
    mx = fmaxf(mx, __shfl_xor(mx, 32));

    if (!__all(mx <= m_s)) {          // defer-max
      float mnew = fmaxf(m_s, mx);
      float scl = fast_exp2((m_s - mnew) * C_SCALE);
      m_s = mnew;
      l_s *= scl;
#pragma unroll
      for (int r = 0; r < 16; r++) { o0[r] *= scl; o1[r] *= scl; }
    }

    const float mC = m_s * C_SCALE;
    float ps = 0.f;
#pragma unroll
    for (int r = 0; r < 16; r++) {
      s0[r] = fast_exp2(fmaf(s0[r], C_SCALE, -mC));
      ps += s0[r];
    }
#pragma unroll
    for (int r = 0; r < 16; r++) {
      s1[r] = fast_exp2(fmaf(s1[r], C_SCALE, -mC));
      ps += s1[r];
    }
    ps += __shfl_xor(ps, 32);
    l_s += ps;

#pragma unroll
    for (int rg = 0; rg < 4; rg++) {
      u16x4 p0, p1;
#pragma unroll
      for (int i = 0; i < 4; i++) {
        p0[i] = f2bf_trunc(s0[rg * 4 + i]);
        p1[i] = f2bf_trunc(s1[rg * 4 + i]);
      }
      *reinterpret_cast<u16x4*>(ldsp(myP, swz(l31, rg * 8 + hi * 4))) = p0;
      *reinterpret_cast<u16x4*>(ldsp(myP, swz(l31, 32 + rg * 8 + hi * 4))) = p1;
    }

    short8 pf[4];
#pragma unroll
    for (int ks = 0; ks < 4; ks++)
      pf[ks] = *reinterpret_cast<const short8*>(
          ldsp(myP, swz(l31, ks * 16 + hi * 8)));
    __builtin_amdgcn_s_setprio(1);
#pragma unroll
    for (int ks = 0; ks < 4; ks++) {
      short8 vf0 = *reinterpret_cast<const short8*>(
          ldsp((unsigned short*)sVt[cur], swz(l31, ks * 16 + hi * 8)));
      o0 = __builtin_amdgcn_mfma_f32_32x32x16_bf16(vf0, pf[ks], o0, 0, 0, 0);
      short8 vf1 = *reinterpret_cast<const short8*>(
          ldsp((unsigned short*)sVt[cur], swz(32 + l31, ks * 16 + hi * 8)));
      o1 = __builtin_amdgcn_mfma_f32_32x32x16_bf16(vf1, pf[ks], o1, 0, 0, 0);
    }
    __builtin_amdgcn_s_setprio(0);

    if (t + 1 < ktiles) {
      stage_write(st, sK[cur ^ 1], sVt[cur ^ 1], tid);
      __syncthreads();
    }
  }

  float inv = 1.f / l_s;
  float* op = &out[(size_t)(rowb + qrow) * D_ + h * 64];
#pragma unroll
  for (int rg = 0; rg < 4; rg++) {
    f32x4 v0, v1;
#pragma unroll
    for (int i = 0; i < 4; i++) {
      v0[i] = o0[rg * 4 + i] * inv;
      v1[i] = o1[rg * 4 + i] * inv;
    }
    *reinterpret_cast<f32x4*>(&op[rg * 8 + hi * 4]) = v0;
    *reinterpret_cast<f32x4*>(&op[32 + rg * 8 + hi * 4]) = v1;
  }
}

extern "C" void kernel_launch(void* const* d_in, const int* in_sizes, int n_in,
                              void* d_out, int out_size, void* d_ws, size_t ws_size,
                              hipStream_t stream) {
  const float* x    = (const float*)d_in[0];
  const float* W    = (const float*)d_in[1];
  const float* bias = (const float*)d_in[2];
  float* out = (float*)d_out;
  char* ws = (char*)d_ws;
  unsigned short* xb  = (unsigned short*)(ws);                    // 8 MB
  unsigned short* wt  = (unsigned short*)(ws + (8u << 20));       // 6 MB
  unsigned short* qk  = (unsigned short*)(ws + (14u << 20));      // 16 MB
  unsigned short* vTb = (unsigned short*)(ws + (30u << 20));      // 8 MB

  conv_x_kernel<<<4096, 256, 0, stream>>>(x, xb);
  transpose_w_kernel<<<dim3(48, 16), 256, 0, stream>>>(W, wt);
  qkv_gemm_kernel<<<dim3(24, 32), 256, 0, stream>>>(xb, wt, bias, qk, vTb);
  attn_kernel<<<1024, 128, 0, stream>>>(qk, vTb, out);
}

// Round 8
// 104.423 us; speedup vs baseline: 2.6097x; 1.0434x over previous
//
#include <hip/hip_runtime.h>
#include <hip/hip_bf16.h>

typedef __attribute__((ext_vector_type(8))) short short8;
typedef __attribute__((ext_vector_type(8))) unsigned short u16x8;
typedef __attribute__((ext_vector_type(4))) unsigned short u16x4;
typedef __attribute__((ext_vector_type(4))) float f32x4;
typedef __attribute__((ext_vector_type(16))) float f32x16;
typedef __attribute__((ext_vector_type(4))) int int4v;

#define S_  2048
#define D_  1024
#define F3  3072
#define QKLD 2048                  // qk buffer: row s -> [h][q 64 | k 64]
#define LOG2E 1.4426950408889634f
#define C_SCALE (0.125f * LOG2E)   // 1/sqrt(64) folded into exp2

__device__ __forceinline__ unsigned short f2bf(float f) {
  unsigned int u = __builtin_bit_cast(unsigned int, f);
  u += 0x7fffu + ((u >> 16) & 1u);
  return (unsigned short)(u >> 16);
}
__device__ __forceinline__ float fast_exp2(float x) {
  float r;
  asm("v_exp_f32 %0, %1" : "=v"(r) : "v"(x));
  return r;
}
__device__ __forceinline__ int cvtpk_bf16(float lo, float hi) {
  int r;
  asm("v_cvt_pk_bf16_f32 %0, %1, %2" : "=v"(r) : "v"(lo), "v"(hi));
  return r;
}
// C-layout (32x32, 16 regs p0..p7 = half) -> MFMA B-operand frag, in-register.
// v_permlane32_swap_b32 dst,src: dst.hi32lanes <-> src.lo32lanes.
// swap(wA<-dst, wC<-src): wA={lo:s(0,1) hi:s(8,9)}, wC={lo:s(4,5) hi:s(12,13)}
// swap(wB, wD):           wB={lo:s(2,3) hi:s(10,11)}, wD={lo:s(6,7) hi:s(14,15)}
// frag [wA,wB,wC,wD]: lane word j holds s = (lane>>5)*8 + 2j,2j+1  (VERIFIED map)
__device__ __forceinline__ short8 mkfrag(float p0, float p1, float p2, float p3,
                                         float p4, float p5, float p6, float p7) {
  int wA = cvtpk_bf16(p0, p1);
  int wB = cvtpk_bf16(p2, p3);
  int wC = cvtpk_bf16(p4, p5);
  int wD = cvtpk_bf16(p6, p7);
  asm volatile("v_permlane32_swap_b32 %0, %1" : "+v"(wA), "+v"(wC));
  asm volatile("v_permlane32_swap_b32 %0, %1" : "+v"(wB), "+v"(wD));
  int4v f = {wA, wB, wC, wD};
  return __builtin_bit_cast(short8, f);
}

// XOR swizzle for 128B LDS rows (8 x 16B chunks), 3-bit key
__device__ __forceinline__ int swz(int row, int col) {    // -> BYTE offset
  int byte = (row << 7) + (col << 1);
  return byte ^ ((((row & 7) ^ ((row >> 3) & 7)) << 4));
}
__device__ __forceinline__ unsigned short* ldsp(unsigned short* base, int byteoff) {
  return (unsigned short*)((char*)base + byteoff);
}

// ---------------- x (f32) -> bf16 ----------------
__global__ __launch_bounds__(256) void conv_x_kernel(const float* __restrict__ x,
                                                     unsigned short* __restrict__ xb) {
  int i = (blockIdx.x * 256 + threadIdx.x) * 4;
  f32x4 v = *reinterpret_cast<const f32x4*>(&x[i]);
  u16x4 o;
  o[0] = f2bf(v[0]); o[1] = f2bf(v[1]); o[2] = f2bf(v[2]); o[3] = f2bf(v[3]);
  *reinterpret_cast<u16x4*>(&xb[i]) = o;
}

// ---------------- W [1024][3072] f32 -> Wt [3072][1024] bf16 ----------------
__global__ __launch_bounds__(256) void transpose_w_kernel(const float* __restrict__ W,
                                                          unsigned short* __restrict__ Wt) {
  __shared__ float tile[64][65];
  int nt = blockIdx.x;
  int kt = blockIdx.y;
  int tid = threadIdx.x;
#pragma unroll
  for (int i = 0; i < 16; i++) {
    int idx = tid + i * 256;
    int r = idx >> 6, c = idx & 63;
    tile[r][c] = W[(size_t)(kt * 64 + r) * F3 + nt * 64 + c];
  }
  __syncthreads();
#pragma unroll
  for (int i = 0; i < 16; i++) {
    int idx = tid + i * 256;
    int rn = idx >> 6, ck = idx & 63;
    Wt[(size_t)(nt * 64 + rn) * D_ + kt * 64 + ck] = f2bf(tile[ck][rn]);
  }
}

// ------- GEMM: BK=64, gload_lds staging + 128B-row XOR swizzle, split epilogue ------
__global__ __launch_bounds__(256) void qkv_gemm_kernel(const unsigned short* __restrict__ A,
                                                       const unsigned short* __restrict__ Bt,
                                                       const float* __restrict__ bias,
                                                       unsigned short* __restrict__ qk,
                                                       unsigned short* __restrict__ vT) {
  constexpr int K = D_;
  __shared__ unsigned short sA[128 * 64];    // 16 KB, rows 128B, swizzled
  __shared__ unsigned short sB[128 * 64];
  int bn = blockIdx.x, bm = blockIdx.y;
  int tid = threadIdx.x;
  int wid = tid >> 6, lane = tid & 63;
  int wr = wid >> 1, wc = wid & 1;
  int lh = lane >> 4, l15 = lane & 15;
  f32x4 acc[4][4] = {};

  // staging: chunk c = tid + i*256 -> row=c>>3 (0..127), slot=c&7; source pre-swizzled
  const int r0 = tid >> 3;                   // 0..31
  const int m0 = tid & 7;
  const unsigned short* gAi[4];
  const unsigned short* gBi[4];
#pragma unroll
  for (int i = 0; i < 4; i++) {
    int row = r0 + 32 * i;
    int key = (row ^ (row >> 3)) & 7;
    int col = (m0 ^ key) * 8;
    gAi[i] = &A[(size_t)(bm * 128 + row) * K + col];
    gBi[i] = &Bt[(size_t)(bn * 128 + row) * K + col];
  }

  for (int k0 = 0; k0 < K; k0 += 64) {
#pragma unroll
    for (int i = 0; i < 4; i++)
      __builtin_amdgcn_global_load_lds((const unsigned int*)(gAi[i] + k0),
                                       (unsigned int*)(&sA[i * 2048 + wid * 512]), 16, 0, 0);
#pragma unroll
    for (int i = 0; i < 4; i++)
      __builtin_amdgcn_global_load_lds((const unsigned int*)(gBi[i] + k0),
                                       (unsigned int*)(&sB[i * 2048 + wid * 512]), 16, 0, 0);
    asm volatile("s_waitcnt vmcnt(0)" ::: "memory");
    __syncthreads();

#pragma unroll
    for (int ksub = 0; ksub < 2; ksub++) {
      short8 af[4], bf[4];
#pragma unroll
      for (int m = 0; m < 4; m++) {
        int ar = wr * 64 + m * 16 + l15;
        int ab = (ar << 7) + ((((ksub << 2) | lh) ^ ((ar ^ (ar >> 3)) & 7)) << 4);
        af[m] = *reinterpret_cast<const short8*>((const char*)sA + ab);
      }
#pragma unroll
      for (int n = 0; n < 4; n++) {
        int br = wc * 64 + n * 16 + l15;
        int bb = (br << 7) + ((((ksub << 2) | lh) ^ ((br ^ (br >> 3)) & 7)) << 4);
        bf[n] = *reinterpret_cast<const short8*>((const char*)sB + bb);
      }
#pragma unroll
      for (int m = 0; m < 4; m++)
#pragma unroll
        for (int n = 0; n < 4; n++)
          acc[m][n] = __builtin_amdgcn_mfma_f32_16x16x32_bf16(af[m], bf[n], acc[m][n], 0, 0, 0);
    }
    __syncthreads();
  }

  int row0 = bm * 128 + wr * 64;
  int col0 = bn * 128 + wc * 64;
  const int bn3 = bn % 3;
  const int vside = (bn3 == 1) ? 0 : (bn3 == 2) ? 1 : -1;

  if (wc == vside) {
    // V epilogue: transpose 64s x 64d via own LDS region, then coalesced 128B-row stores
    unsigned short* tile = wr ? sB : sA;          // 8KB = [64 d][64 s], swizzled rows
    const int h = col0 / 192;                     // group base has w==128 -> d = 0..63
#pragma unroll
    for (int n = 0; n < 4; n++) {
      int d = n * 16 + l15;
      float bv = bias[col0 + n * 16 + l15];
#pragma unroll
      for (int m = 0; m < 4; m++) {
        u16x4 pk;
#pragma unroll
        for (int r = 0; r < 4; r++) pk[r] = f2bf(acc[m][n][r] + bv);
        *reinterpret_cast<u16x4*>(ldsp(tile, swz(d, m * 16 + lh * 4))) = pk;
      }
    }
    const int bbat = row0 >> 11, s0g = row0 & 2047;
    unsigned short* vrow = &vT[(size_t)(bbat * 16 + h) * 64 * S_ + s0g];
#pragma unroll
    for (int i = 0; i < 8; i++) {
      int c = lane + i * 64;
      int rrow = c >> 3, blk = c & 7;
      short8 v = *reinterpret_cast<const short8*>(ldsp(tile, swz(rrow, blk * 8)));
      *reinterpret_cast<short8*>(&vrow[(size_t)rrow * S_ + blk * 8]) = v;
    }
  } else {
    // Q/K epilogue (all 4 n-groups have w<128 on this side)
#pragma unroll
    for (int n = 0; n < 4; n++) {
      int g = col0 + n * 16;
      int h = g / 192;
      int w = g % 192;
      float bv = bias[g + l15];
      int colq = h * 128 + w + l15;
#pragma unroll
      for (int m = 0; m < 4; m++)
#pragma unroll
        for (int r = 0; r < 4; r++) {
          int row = row0 + m * 16 + lh * 4 + r;
          qk[(size_t)row * QKLD + colq] = f2bf(acc[m][n][r] + bv);
        }
    }
  }
}

// ---------------- causal flash attention: 32x32 MFMA, in-register P ----------------
struct Stage { u16x8 k[4]; u16x8 v[4]; };

__device__ __forceinline__ void stage_load(Stage& st, const unsigned short* kb,
                                           const unsigned short* vb, int tid) {
#pragma unroll
  for (int i = 0; i < 4; i++) {
    int c = tid + i * 128;
    int row = c >> 3, col = (c & 7) * 8;
    st.k[i] = *reinterpret_cast<const u16x8*>(kb + (size_t)row * QKLD + col);
    st.v[i] = *reinterpret_cast<const u16x8*>(vb + (size_t)row * S_ + col);
  }
}
__device__ __forceinline__ void stage_write(const Stage& st, unsigned short* sk,
                                            unsigned short* sv, int tid) {
#pragma unroll
  for (int i = 0; i < 4; i++) {
    int c = tid + i * 128;
    int row = c >> 3, col = (c & 7) * 8;
    *reinterpret_cast<u16x8*>(ldsp(sk, swz(row, col))) = st.k[i];
    *reinterpret_cast<u16x8*>(ldsp(sv, swz(row, col))) = st.v[i];
  }
}

__global__ __launch_bounds__(128, 2) void attn_kernel(const unsigned short* __restrict__ qk,
                                                      const unsigned short* __restrict__ vT,
                                                      float* __restrict__ out) {
  __shared__ unsigned short sK[2][4096];     // [64 k][64 d] swizzled
  __shared__ unsigned short sVt[2][4096];    // [64 d][64 k] swizzled

  // Strip map balanced for stride-256 co-residency (XCD round-robin):
  // CU hosts {lin, lin+256, lin+512, lin+768} -> qt {r,15-r,16+r,31-r}, sum=66 iters,
  // same bh (L2 locality for K/V).
  const int lin = blockIdx.x;
  const int j = lin >> 8;
  const int r8 = (lin >> 5) & 7;
  const int bh = lin & 31;
  const int qt = (j == 0) ? r8 : (j == 1) ? 15 - r8 : (j == 2) ? 16 + r8 : 31 - r8;

  const int b = bh >> 4, h = bh & 15;
  const int tid = threadIdx.x;
  const int wid = tid >> 6, lane = tid & 63;
  const int l31 = lane & 31, hi = lane >> 5;
  const int rowb = b * S_;

  const unsigned short* kbase = qk + (size_t)rowb * QKLD + h * 128 + 64;
  const unsigned short* vbase = vT + (size_t)bh * 64 * S_;

  const int ktiles = qt + 1;
  const int qrow = qt * 64 + wid * 32 + l31;   // this lane's q-row

  short8 qf[4];
#pragma unroll
  for (int st = 0; st < 4; st++)
    qf[st] = *reinterpret_cast<const short8*>(
        qk + (size_t)(rowb + qrow) * QKLD + h * 128 + st * 16 + hi * 8);

  float m_s = -1e30f, l_s = 0.f;
  f32x16 o0, o1;
#pragma unroll
  for (int r = 0; r < 16; r++) { o0[r] = 0.f; o1[r] = 0.f; }

  Stage st;
  stage_load(st, kbase, vbase, tid);
  stage_write(st, sK[0], sVt[0], tid);
  __syncthreads();

  for (int t = 0; t < ktiles; t++) {
    const int cur = t & 1;
    if (t + 1 < ktiles)
      stage_load(st, kbase + (size_t)(t + 1) * 64 * QKLD, vbase + (t + 1) * 64, tid);

    const bool diag = (t == qt);
    f32x16 s0, s1;
    __builtin_amdgcn_s_setprio(1);
    {
      f32x16 a;
#pragma unroll
      for (int r = 0; r < 16; r++) a[r] = 0.f;
#pragma unroll
      for (int stp = 0; stp < 4; stp++) {
        short8 kf = *reinterpret_cast<const short8*>(
            ldsp((unsigned short*)sK[cur], swz(l31, stp * 16 + hi * 8)));
        a = __builtin_amdgcn_mfma_f32_32x32x16_bf16(kf, qf[stp], a, 0, 0, 0);
      }
      s0 = a;
    }
    if (!(diag && wid == 0)) {
      f32x16 a;
#pragma unroll
      for (int r = 0; r < 16; r++) a[r] = 0.f;
#pragma unroll
      for (int stp = 0; stp < 4; stp++) {
        short8 kf = *reinterpret_cast<const short8*>(
            ldsp((unsigned short*)sK[cur], swz(32 + l31, stp * 16 + hi * 8)));
        a = __builtin_amdgcn_mfma_f32_32x32x16_bf16(kf, qf[stp], a, 0, 0, 0);
      }
      s1 = a;
    } else {
#pragma unroll
      for (int r = 0; r < 16; r++) s1[r] = -1e30f;
    }
    __builtin_amdgcn_s_setprio(0);

    if (diag) {
      const int kb0 = t * 64;
      if (wid == 0) {
#pragma unroll
        for (int r = 0; r < 16; r++) {
          int kg = kb0 + (r & 3) + 8 * (r >> 2) + 4 * hi;
          if (kg > qrow) s0[r] = -1e30f;
        }
      } else {
#pragma unroll
        for (int r = 0; r < 16; r++) {
          int kg = kb0 + 32 + (r & 3) + 8 * (r >> 2) + 4 * hi;
          if (kg > qrow) s1[r] = -1e30f;
        }
      }
    }

    float mx = s0[0];
#pragma unroll
    for (int r = 1; r < 16; r++) mx = fmaxf(mx, s0[r]);
#pragma unroll
    for (int r = 0; r < 16; r++) mx = fmaxf(mx, s1[r]);
    mx = fmaxf(mx, __shfl_xor(mx, 32));

    if (!__all(mx <= m_s)) {          // defer-max
      float mnew = fmaxf(m_s, mx);
      float scl = fast_exp2((m_s - mnew) * C_SCALE);
      m_s = mnew;
      l_s *= scl;
#pragma unroll
      for (int r = 0; r < 16; r++) { o0[r] *= scl; o1[r] *= scl; }
    }

    const float mC = m_s * C_SCALE;
    float ps = 0.f;
#pragma unroll
    for (int r = 0; r < 16; r++) {
      s0[r] = fast_exp2(fmaf(s0[r], C_SCALE, -mC));
      ps += s0[r];
    }
#pragma unroll
    for (int r = 0; r < 16; r++) {
      s1[r] = fast_exp2(fmaf(s1[r], C_SCALE, -mC));
      ps += s1[r];
    }
    ps += __shfl_xor(ps, 32);
    l_s += ps;

    // P -> MFMA B-operand fully in-register (no LDS round-trip)
    short8 pf[4];
    pf[0] = mkfrag(s0[0], s0[1], s0[2], s0[3], s0[4], s0[5], s0[6], s0[7]);
    pf[1] = mkfrag(s0[8], s0[9], s0[10], s0[11], s0[12], s0[13], s0[14], s0[15]);
    pf[2] = mkfrag(s1[0], s1[1], s1[2], s1[3], s1[4], s1[5], s1[6], s1[7]);
    pf[3] = mkfrag(s1[8], s1[9], s1[10], s1[11], s1[12], s1[13], s1[14], s1[15]);

    __builtin_amdgcn_s_setprio(1);
#pragma unroll
    for (int ks = 0; ks < 4; ks++) {
      short8 vf0 = *reinterpret_cast<const short8*>(
          ldsp((unsigned short*)sVt[cur], swz(l31, ks * 16 + hi * 8)));
      o0 = __builtin_amdgcn_mfma_f32_32x32x16_bf16(vf0, pf[ks], o0, 0, 0, 0);
      short8 vf1 = *reinterpret_cast<const short8*>(
          ldsp((unsigned short*)sVt[cur], swz(32 + l31, ks * 16 + hi * 8)));
      o1 = __builtin_amdgcn_mfma_f32_32x32x16_bf16(vf1, pf[ks], o1, 0, 0, 0);
    }
    __builtin_amdgcn_s_setprio(0);

    if (t + 1 < ktiles) {
      stage_write(st, sK[cur ^ 1], sVt[cur ^ 1], tid);
      __syncthreads();
    }
  }

  float inv = 1.f / l_s;
  float* op = &out[(size_t)(rowb + qrow) * D_ + h * 64];
#pragma unroll
  for (int rg = 0; rg < 4; rg++) {
    f32x4 v0, v1;
#pragma unroll
    for (int i = 0; i < 4; i++) {
      v0[i] = o0[rg * 4 + i] * inv;
      v1[i] = o1[rg * 4 + i] * inv;
    }
    *reinterpret_cast<f32x4*>(&op[rg * 8 + hi * 4]) = v0;
    *reinterpret_cast<f32x4*>(&op[32 + rg * 8 + hi * 4]) = v1;
  }
}

extern "C" void kernel_launch(void* const* d_in, const int* in_sizes, int n_in,
                              void* d_out, int out_size, void* d_ws, size_t ws_size,
                              hipStream_t stream) {
  const float* x    = (const float*)d_in[0];
  const float* W    = (const float*)d_in[1];
  const float* bias = (const float*)d_in[2];
  float* out = (float*)d_out;
  char* ws = (char*)d_ws;
  unsigned short* xb  = (unsigned short*)(ws);                    // 8 MB
  unsigned short* wt  = (unsigned short*)(ws + (8u << 20));       // 6 MB
  unsigned short* qk  = (unsigned short*)(ws + (14u << 20));      // 16 MB
  unsigned short* vTb = (unsigned short*)(ws + (30u << 20));      // 8 MB

  conv_x_kernel<<<4096, 256, 0, stream>>>(x, xb);
  transpose_w_kernel<<<dim3(48, 16), 256, 0, stream>>>(W, wt);
  qkv_gemm_kernel<<<dim3(24, 32), 256, 0, stream>>>(xb, wt, bias, qk, vTb);
  attn_kernel<<<1024, 128, 0, stream>>>(qk, vTb, out);
}